// Round 17
// baseline (5059.441 us; speedup 1.0000x reference)
//
#include <hip/hip_runtime.h>
#include <math.h>

#define N_NODES 1024
#define HID 64
#define BATCH 16
#define TSTEPS 288
#define PWIN 24
#define PL 12
#define EMB 16
#define HOR 12

typedef __attribute__((ext_vector_type(4))) short short4_t;
typedef _Float16 f16x8 __attribute__((ext_vector_type(8)));
typedef _Float16 f16x4 __attribute__((ext_vector_type(4)));
typedef float f32x4 __attribute__((ext_vector_type(4)));

// block per (ngrp, p, bhalf): lane = n (coalesced 128B stores); 8 b's per block.
__global__ __launch_bounds__(256) void embedq6_k(
    const float* __restrict__ src, const float* __restrict__ vw,
    _Float16* __restrict__ xqT)
{
    int p = blockIdx.y;
    int n0 = blockIdx.x * 64;
    int bh = blockIdx.z;              // b in [bh*8, bh*8+8)
    int t = threadIdx.x;
    int lane = t & 63, wid = t >> 6;
    __shared__ float sv[96][64];      // [(b-bh*8)*12+tt][n]
    __shared__ float wvs[PL*HID];
    __shared__ float pe[64];
    for (int r = wid; r < 96; r += 4) {
        int b = bh*8 + r/12, tt = r % 12;
        sv[r][lane] = src[((size_t)b*TSTEPS + p*PL + tt)*N_NODES + n0 + lane];
    }
    for (int i = t; i < PL*HID; i += 256) wvs[i] = vw[i];
    if (t < 64) {
        float d = expf(-(float)(t & ~1) * (float)(9.210340371976184/64.0));
        float arg = (float)p * d;
        pe[t] = (t & 1) ? cosf(arg) : sinf(arg);
    }
    __syncthreads();
#pragma unroll 1
    for (int bb = 0; bb < 2; ++bb) {
        int br = wid*2 + bb;
        int b = bh*8 + br;
        float svr[12];
#pragma unroll
        for (int tt = 0; tt < 12; ++tt) svr[tt] = sv[br*12 + tt][lane];
        _Float16* xp = xqT + ((size_t)p << 20) + (size_t)b*64*1024 + n0 + lane;
#pragma unroll 1
        for (int h0 = 0; h0 < 64; h0 += 8) {
#pragma unroll
            for (int hh = 0; hh < 8; ++hh) {
                int h = h0 + hh;
                float d = pe[h];
#pragma unroll
                for (int tt = 0; tt < 12; ++tt) d += svr[tt] * wvs[tt*HID + h];
                xp[(size_t)h*1024] = (_Float16)d;
            }
        }
    }
}

// A[n][m] = softmax_m(relu(emb[n]·emb[m])), written as plain f16.
__global__ __launch_bounds__(256) void adj_k(const float* __restrict__ emb,
    _Float16* __restrict__ Ahi)
{
    __shared__ float en[EMB];
    __shared__ float red[256];
    int n = blockIdx.x, t = threadIdx.x;
    if (t < EMB) en[t] = emb[n*EMB + t];
    __syncthreads();
    float v[4]; float mx = 0.f;
#pragma unroll
    for (int q = 0; q < 4; ++q) {
        int m = q*256 + t;
        float dot = 0.f;
#pragma unroll
        for (int e = 0; e < EMB; ++e) dot += en[e]*emb[m*EMB + e];
        v[q] = fmaxf(dot, 0.f);
        mx = fmaxf(mx, v[q]);
    }
    red[t] = mx; __syncthreads();
    for (int s2 = 128; s2 > 0; s2 >>= 1) {
        if (t < s2) red[t] = fmaxf(red[t], red[t + s2]);
        __syncthreads();
    }
    mx = red[0]; __syncthreads();
    float sum = 0.f;
#pragma unroll
    for (int q = 0; q < 4; ++q) { v[q] = expf(v[q] - mx); sum += v[q]; }
    red[t] = sum; __syncthreads();
    for (int s2 = 128; s2 > 0; s2 >>= 1) {
        if (t < s2) red[t] += red[t + s2];
        __syncthreads();
    }
    float inv = 1.f / red[0];
#pragma unroll
    for (int q = 0; q < 4; ++q)
        Ahi[(size_t)n*N_NODES + q*256 + t] = (_Float16)(v[q]*inv);
}

// gwT2[e][kc4][OUT][4] <- gwl[e][kc][o]
template<int OUT>
__global__ __launch_bounds__(256) void wtrans2_k(
    const float* __restrict__ gwl, float* __restrict__ gwT2)
{
    int idx = blockIdx.x*256 + threadIdx.x;
    int o = idx % OUT;
    int rest = idx / OUT;
    int kc = rest & 255;
    int e = rest >> 8;
    gwT2[(((size_t)e*64 + (kc >> 2))*OUT + o)*4 + (kc & 3)] = gwl[idx];
}

// W16[n][kc4][OUT][4] f16 = sum_e emb[n][e]*gwT2[e][kc4][o][kj].
template<int OUT>
__global__ __launch_bounds__(256) void wnodeq3_k(
    const float* __restrict__ emb, const float* __restrict__ gwT2,
    _Float16* __restrict__ W16)
{
    int t = threadIdx.x;
    int n0 = blockIdx.x * 4;
    int y = blockIdx.y;
    const int G = 256/OUT;
    int o = t % OUT, g = t / OUT;
    __shared__ float se[4][EMB];
    if (t < 4*EMB) se[t >> 4][t & 15] = emb[(n0 + (t >> 4))*EMB + (t & 15)];
    __syncthreads();
    for (int kc4 = y*8 + g; kc4 < (y+1)*8; kc4 += G) {
        f32x4 s[4];
#pragma unroll
        for (int ng = 0; ng < 4; ++ng) s[ng] = (f32x4){0.f,0.f,0.f,0.f};
        const float* gp = gwT2 + ((size_t)kc4*OUT + o)*4;
#pragma unroll 4
        for (int e = 0; e < EMB; ++e) {
            f32x4 gv = *(const f32x4*)(gp + (size_t)e*(64*OUT*4));
#pragma unroll
            for (int ng = 0; ng < 4; ++ng) {
                float c = se[ng][e];
                s[ng] += gv * c;
            }
        }
#pragma unroll
        for (int ng = 0; ng < 4; ++ng) {
            f16x4 q;
            q[0] = (_Float16)s[ng][0]; q[1] = (_Float16)s[ng][1];
            q[2] = (_Float16)s[ng][2]; q[3] = (_Float16)s[ng][3];
            *(f16x4*)(W16 + (((size_t)(n0+ng)*64 + kc4)*OUT + o)*4) = q;
        }
    }
}

__global__ __launch_bounds__(256) void bias_k(const float* __restrict__ emb,
                        const float* __restrict__ gbl, float* __restrict__ bn, int OUT)
{
    int idx = blockIdx.x*256 + threadIdx.x;
    if (idx >= N_NODES*OUT) return;
    int n = idx / OUT, o = idx % OUT;
    float s = 0.f;
#pragma unroll
    for (int e = 0; e < EMB; ++e) s += emb[n*EMB + e]*gbl[e*OUT + o];
    bn[idx] = s;
}

// Batched A@x for 8 consecutive steps. grid (16,16,8), f16 out.
__global__ __launch_bounds__(256) void gemmaxb_k(
    const _Float16* __restrict__ Ahi, const _Float16* __restrict__ xqT_b,
    _Float16* __restrict__ pAx16)
{
    int st = blockIdx.z;
    const _Float16* BT16 = xqT_b + ((size_t)st << 20);
    _Float16* out = pAx16 + ((size_t)st << 20);
    __shared__ _Float16 Ash[64*72];
    __shared__ _Float16 Bsh[64*72];
    int t = threadIdx.x;
    int l = t & 63, w = t >> 6;
    int wr = w >> 1, wc = w & 1;
    int r0 = blockIdx.y*64, c0 = blockIdx.x*64;
    f32x4 acc[2][2];
#pragma unroll
    for (int i = 0; i < 2; ++i)
#pragma unroll
        for (int j = 0; j < 2; ++j) acc[i][j] = (f32x4){0.f,0.f,0.f,0.f};
    int arow = wr*32 + (l & 15);
    int brow = wc*32 + (l & 15);
    int koff = (l >> 4)*8;
    for (int k0 = 0; k0 < 1024; k0 += 64) {
        __syncthreads();
#pragma unroll
        for (int c = 0; c < 2; ++c) {
            int id = t + 256*c;
            int row = id >> 3, k8 = id & 7;
            *(f16x8*)(&Ash[row*72 + k8*8]) =
                *(const f16x8*)(&Ahi[(size_t)(r0+row)*1024 + k0 + k8*8]);
            *(f16x8*)(&Bsh[row*72 + k8*8]) =
                *(const f16x8*)(&BT16[(size_t)(c0+row)*1024 + k0 + k8*8]);
        }
        __syncthreads();
#pragma unroll
        for (int kk = 0; kk < 2; ++kk) {
            int ko = kk*32 + koff;
            f16x8 ah0 = *(const f16x8*)(&Ash[(size_t)arow*72 + ko]);
            f16x8 ah1 = *(const f16x8*)(&Ash[(size_t)(arow+16)*72 + ko]);
            f16x8 bh0 = *(const f16x8*)(&Bsh[(size_t)brow*72 + ko]);
            f16x8 bh1 = *(const f16x8*)(&Bsh[(size_t)(brow+16)*72 + ko]);
            acc[0][0] = __builtin_amdgcn_mfma_f32_16x16x32_f16(ah0, bh0, acc[0][0], 0, 0, 0);
            acc[0][1] = __builtin_amdgcn_mfma_f32_16x16x32_f16(ah0, bh1, acc[0][1], 0, 0, 0);
            acc[1][0] = __builtin_amdgcn_mfma_f32_16x16x32_f16(ah1, bh0, acc[1][0], 0, 0, 0);
            acc[1][1] = __builtin_amdgcn_mfma_f32_16x16x32_f16(ah1, bh1, acc[1][1], 0, 0, 0);
        }
    }
#pragma unroll
    for (int fr = 0; fr < 2; ++fr)
#pragma unroll
        for (int fc = 0; fc < 2; ++fc) {
            int orow = r0 + wr*32 + fr*16 + ((l >> 4) << 2);
            int ocol = c0 + wc*32 + fc*16 + (l & 15);
#pragma unroll
            for (int i = 0; i < 4; ++i)
                out[(size_t)(orow+i)*1024 + ocol] = (_Float16)acc[fr][fc][i];
        }
}

// Per-step recurrent GEMMs: job 0: A@hT16 -> pAh; job 1: A@zhT16 -> pAzh.
__global__ __launch_bounds__(256) void gemm16_k(
    const _Float16* __restrict__ Ahi,
    const _Float16* __restrict__ hT16, const _Float16* __restrict__ zhT16,
    float* __restrict__ pAh, float* __restrict__ pAzh, int zoff)
{
    int z = zoff + blockIdx.z;
    int job = z >> 1, ks = z & 1;
    int kbase = ks << 9;
    float* out = (job ? pAzh : pAh) + ((size_t)ks << 20);
    const _Float16* BT16 = job ? zhT16 : hT16;
    __shared__ _Float16 Ash[64*72];
    __shared__ _Float16 Bsh[64*72];
    int t = threadIdx.x;
    int l = t & 63, w = t >> 6;
    int wr = w >> 1, wc = w & 1;
    int r0 = blockIdx.y*64, c0 = blockIdx.x*64;
    f32x4 acc[2][2];
#pragma unroll
    for (int i = 0; i < 2; ++i)
#pragma unroll
        for (int j = 0; j < 2; ++j) acc[i][j] = (f32x4){0.f,0.f,0.f,0.f};
    int arow = wr*32 + (l & 15);
    int brow = wc*32 + (l & 15);
    int koff = (l >> 4)*8;
    for (int k0 = kbase; k0 < kbase + 512; k0 += 64) {
        __syncthreads();
#pragma unroll
        for (int c = 0; c < 2; ++c) {
            int id = t + 256*c;
            int row = id >> 3, k8 = id & 7;
            *(f16x8*)(&Ash[row*72 + k8*8]) =
                *(const f16x8*)(&Ahi[(size_t)(r0+row)*1024 + k0 + k8*8]);
            *(f16x8*)(&Bsh[row*72 + k8*8]) =
                *(const f16x8*)(&BT16[(size_t)(c0+row)*1024 + k0 + k8*8]);
        }
        __syncthreads();
#pragma unroll
        for (int kk = 0; kk < 2; ++kk) {
            int ko = kk*32 + koff;
            f16x8 ah0 = *(const f16x8*)(&Ash[(size_t)arow*72 + ko]);
            f16x8 ah1 = *(const f16x8*)(&Ash[(size_t)(arow+16)*72 + ko]);
            f16x8 bh0 = *(const f16x8*)(&Bsh[(size_t)brow*72 + ko]);
            f16x8 bh1 = *(const f16x8*)(&Bsh[(size_t)(brow+16)*72 + ko]);
            acc[0][0] = __builtin_amdgcn_mfma_f32_16x16x32_f16(ah0, bh0, acc[0][0], 0, 0, 0);
            acc[0][1] = __builtin_amdgcn_mfma_f32_16x16x32_f16(ah0, bh1, acc[0][1], 0, 0, 0);
            acc[1][0] = __builtin_amdgcn_mfma_f32_16x16x32_f16(ah1, bh0, acc[1][0], 0, 0, 0);
            acc[1][1] = __builtin_amdgcn_mfma_f32_16x16x32_f16(ah1, bh1, acc[1][1], 0, 0, 0);
        }
    }
#pragma unroll
    for (int fr = 0; fr < 2; ++fr)
#pragma unroll
        for (int fc = 0; fc < 2; ++fc) {
            int orow = r0 + wr*32 + fr*16 + ((l >> 4) << 2);
            int ocol = c0 + wc*32 + fc*16 + (l & 15);
#pragma unroll
            for (int i = 0; i < 4; ++i)
                out[(size_t)(orow+i)*1024 + ocol] = acc[fr][fc][i];
        }
}

// zr[n][b][o] = sigmoid([x,h,Ax,Ah]·W(o,:) + bg); writes zhT16[j][n]=z*h.
// grid 2048: bid = nRaw*2 + oh; block covers 64 o's, all 16 b's.
// Weight loop unroll 8 -> 8 independent 8B loads in flight (R16: MLP-starved
// at 1.2 TB/s, 43us). Accumulation order per output unchanged.
template<int FIRST>
__global__ __launch_bounds__(256) void gate_k(
    const _Float16* __restrict__ xqT16p, const _Float16* __restrict__ pAx16,
    const float* __restrict__ hst, const float* __restrict__ pAh,
    const _Float16* __restrict__ W16, const float* __restrict__ bg,
    float* __restrict__ zr, _Float16* __restrict__ zhT16)
{
    __shared__ float inp[16*256];
    int bid = blockIdx.x;
    int nRaw = bid >> 1, oh = bid & 1;
    int n = ((nRaw & 7) << 7) | (nRaw >> 3);
    int t = threadIdx.x;
    size_t nb = (size_t)n*1024;
    for (int i = t; i < 1024; i += 256) {
        int b = i >> 6, c = i & 63;
        inp[b*256 + c]       = (float)xqT16p[(size_t)i*1024 + n];
        inp[b*256 + 64 + c]  = FIRST ? 0.f : hst[nb + i];
        inp[b*256 + 128 + c] = (float)pAx16[nb + i];
        inp[b*256 + 192 + c] = FIRST ? 0.f : (pAh[nb + i] + pAh[nb + i + 1048576]);
    }
    __syncthreads();
    int o = oh*64 + (t & 63), g = t >> 6;      // 4 groups x 4 batches
    const _Float16* wp = W16 + (size_t)n*32768 + o*4;   // [n][kc4][128][4]
    float bias = bg[n*128 + o];
    float acc[4];
#pragma unroll
    for (int u = 0; u < 4; ++u) acc[u] = 0.f;
#pragma unroll 8
    for (int kc4 = 0; kc4 < 64; ++kc4) {
        f16x4 w4 = *(const f16x4*)(wp + (size_t)kc4*512);
        float w0 = (float)w4[0], w1 = (float)w4[1], w2 = (float)w4[2], w3 = (float)w4[3];
#pragma unroll
        for (int u = 0; u < 4; ++u) {
            float4 iv = *(const float4*)(&inp[(g*4 + u)*256 + kc4*4]);
            acc[u] += w0*iv.x + w1*iv.y + w2*iv.z + w3*iv.w;
        }
    }
#pragma unroll
    for (int u = 0; u < 4; ++u) {
        int b = g*4 + u;
        float pre = acc[u] + bias;
        float val = 1.f/(1.f + expf(-pre));
        zr[((size_t)n*16 + b)*128 + o] = val;
        if (!FIRST && o < 64)
            zhT16[(size_t)(b*64 + o)*1024 + n] = (_Float16)(val * inp[b*256 + 64 + o]);
    }
}

// h_new = r*h + (1-r)*tanh([x, z*h, Ax, Azh]·W + bu). grid 2048: 32 o's/block.
template<int FIRST, int WX>
__global__ __launch_bounds__(256) void upd_k(
    _Float16* __restrict__ xqT16p, const _Float16* __restrict__ pAx16,
    float* __restrict__ hst, const float* __restrict__ pAzh,
    const float* __restrict__ zr, const _Float16* __restrict__ W16,
    const float* __restrict__ bu, _Float16* __restrict__ hT16)
{
    __shared__ float inp[16*256];
    int bid = blockIdx.x;
    int nRaw = bid >> 1, oh = bid & 1;
    int n = ((nRaw & 7) << 7) | (nRaw >> 3);
    int t = threadIdx.x;
    size_t nb = (size_t)n*1024;
    for (int i = t; i < 1024; i += 256) {
        int b = i >> 6, c = i & 63;
        float hv = FIRST ? 0.f : hst[nb + i];
        float zv = zr[((size_t)n*16 + b)*128 + c];
        inp[b*256 + c]       = (float)xqT16p[(size_t)i*1024 + n];
        inp[b*256 + 64 + c]  = zv * hv;
        inp[b*256 + 128 + c] = (float)pAx16[nb + i];
        inp[b*256 + 192 + c] = FIRST ? 0.f : (pAzh[nb + i] + pAzh[nb + i + 1048576]);
    }
    __syncthreads();
    int o = oh*32 + (t & 31), g = t >> 5;      // 8 groups x 2 batches
    const _Float16* wp = W16 + (size_t)n*16384 + o*4;   // [n][kc4][64][4]
    float bias = bu[n*64 + o];
    float acc[2];
    acc[0] = 0.f; acc[1] = 0.f;
#pragma unroll 8
    for (int kc4 = 0; kc4 < 64; ++kc4) {
        f16x4 w4 = *(const f16x4*)(wp + (size_t)kc4*256);
        float w0 = (float)w4[0], w1 = (float)w4[1], w2 = (float)w4[2], w3 = (float)w4[3];
#pragma unroll
        for (int u = 0; u < 2; ++u) {
            float4 iv = *(const float4*)(&inp[(g*2 + u)*256 + kc4*4]);
            acc[u] += w0*iv.x + w1*iv.y + w2*iv.z + w3*iv.w;
        }
    }
#pragma unroll
    for (int u = 0; u < 2; ++u) {
        int b = g*2 + u;
        float r = zr[((size_t)n*16 + b)*128 + 64 + o];
        float hold = FIRST ? 0.f : hst[nb + b*64 + o];
        float hc = tanhf(acc[u] + bias);
        float hn = r*hold + (1.f - r)*hc;
        hst[nb + b*64 + o] = hn;
        hT16[(size_t)(b*64 + o)*1024 + n] = (_Float16)hn;
        if (WX) xqT16p[(size_t)(b*64 + o)*1024 + n] = (_Float16)hn;
    }
}

// out[b][o][n] = h[n][b][:]·ecw[o][:] + ecb[o]
__global__ __launch_bounds__(256) void endconv_k(
    const float* __restrict__ hst, const float* __restrict__ ecw,
    const float* __restrict__ ecb, float* __restrict__ out)
{
    int idx = blockIdx.x*256 + threadIdx.x;
    int n = idx & 1023;
    int o = (idx >> 10) % HOR;
    int b = idx / (HOR*1024);
    float s = ecb[o];
#pragma unroll
    for (int hh = 0; hh < 64; ++hh)
        s += hst[((size_t)n*16 + b)*64 + hh] * ecw[o*64 + hh];
    out[idx] = s;
}

extern "C" void kernel_launch(void* const* d_in, const int* in_sizes, int n_in,
                              void* d_out, int out_size, void* d_ws, size_t ws_size,
                              hipStream_t stream)
{
    const float* source = (const float*)d_in[0];
    const float* emb    = (const float*)d_in[2];
    const float* vw     = (const float*)d_in[3];
    const float* gate_w = (const float*)d_in[4];
    const float* gate_b = (const float*)d_in[5];
    const float* upd_w  = (const float*)d_in[6];
    const float* upd_b  = (const float*)d_in[7];
    const float* ecw    = (const float*)d_in[8];
    const float* ecb    = (const float*)d_in[9];
    float* out = (float*)d_out;

    // ---- workspace carve: ~195 MB ----
    char* p = (char*)d_ws;
    _Float16* Ahi = (_Float16*)p; p += (size_t)1048576*2;    //   2.0 MB
    _Float16* WgQ = (_Float16*)p; p += (size_t)33554432*2;   //  64.0 MB [n][64][128][4] f16
    _Float16* WuQ = (_Float16*)p; p += (size_t)16777216*2;   //  32.0 MB [n][64][64][4] f16
    float* bgn  = (float*)p;  p += (size_t)131072*4;         //   0.5 MB
    float* bun  = (float*)p;  p += (size_t)65536*4;          //   0.25 MB
    _Float16* xqT = (_Float16*)p; p += (size_t)25165824*2;   //  48.0 MB [p][j][n] f16
    float* hbuf = (float*)p;  p += (size_t)1048576*4;        //   4.0 MB h rows f32
    _Float16* hT16 = (_Float16*)p; p += (size_t)1048576*2;   //   2.0 MB h cols f16
    float* zrb  = (float*)p;  p += (size_t)2097152*4;        //   8.0 MB
    _Float16* zhT16 = (_Float16*)p; p += (size_t)1048576*2;  //   2.0 MB (z*h)^T f16
    float* pAh  = (float*)p;  p += (size_t)2097152*4;        //   8.0 MB split-K pair
    _Float16* pAx16 = (_Float16*)p; p += (size_t)8388608*2;  //  16.0 MB 8-step A@x batch
    float* pAzh = (float*)p;  p += (size_t)2097152*4;        //   8.0 MB split-K pair
    float* gwT2 = pAzh;   // 2 MB scratch, aliases pAzh (dead during layer setup)

    embedq6_k<<<dim3(16,24,2), 256, 0, stream>>>(source, vw, xqT);
    adj_k<<<1024, 256, 0, stream>>>(emb, Ahi);

    for (int l = 0; l < 2; ++l) {
        wtrans2_k<128><<<2048, 256, 0, stream>>>(gate_w + (size_t)l*524288, gwT2);
        wnodeq3_k<128><<<dim3(256,8), 256, 0, stream>>>(emb, gwT2, WgQ);
        wtrans2_k<64><<<1024, 256, 0, stream>>>(upd_w + (size_t)l*262144, gwT2);
        wnodeq3_k<64><<<dim3(256,8), 256, 0, stream>>>(emb, gwT2, WuQ);
        bias_k<<<512, 256, 0, stream>>>(emb, gate_b + l*2048, bgn, 128);
        bias_k<<<256, 256, 0, stream>>>(emb, upd_b + l*1024, bun, 64);
        for (int ps = 0; ps < PWIN; ++ps) {
            _Float16* xqT_p = xqT + ((size_t)ps << 20);
            _Float16* pAx_p = pAx16 + ((size_t)(ps & 7) << 20);
            if ((ps & 7) == 0)
                gemmaxb_k<<<dim3(16,16,8), 256, 0, stream>>>(Ahi, xqT_p, pAx16);
            if (ps == 0) {
                gate_k<1><<<2048, 256, 0, stream>>>(xqT_p, pAx_p, hbuf, pAh, WgQ, bgn, zrb, zhT16);
                if (l == 0)
                    upd_k<1,1><<<2048, 256, 0, stream>>>(xqT_p, pAx_p, hbuf, pAzh, zrb, WuQ, bun, hT16);
                else
                    upd_k<1,0><<<2048, 256, 0, stream>>>(xqT_p, pAx_p, hbuf, pAzh, zrb, WuQ, bun, hT16);
            } else {
                gemm16_k<<<dim3(16,16,2), 256, 0, stream>>>(Ahi, hT16, zhT16, pAh, pAzh, 0);
                gate_k<0><<<2048, 256, 0, stream>>>(xqT_p, pAx_p, hbuf, pAh, WgQ, bgn, zrb, zhT16);
                gemm16_k<<<dim3(16,16,2), 256, 0, stream>>>(Ahi, hT16, zhT16, pAh, pAzh, 2);
                if (l == 0)
                    upd_k<0,1><<<2048, 256, 0, stream>>>(xqT_p, pAx_p, hbuf, pAzh, zrb, WuQ, bun, hT16);
                else
                    upd_k<0,0><<<2048, 256, 0, stream>>>(xqT_p, pAx_p, hbuf, pAzh, zrb, WuQ, bun, hT16);
            }
        }
    }
    endconv_k<<<768, 256, 0, stream>>>(hbuf, ecw, ecb, out);
}

// Round 18
// 4089.094 us; speedup vs baseline: 1.2373x; 1.2373x over previous
//
#include <hip/hip_runtime.h>
#include <math.h>

#define N_NODES 1024
#define HID 64
#define BATCH 16
#define TSTEPS 288
#define PWIN 24
#define PL 12
#define EMB 16
#define HOR 12

typedef __attribute__((ext_vector_type(4))) short short4_t;
typedef _Float16 f16x8 __attribute__((ext_vector_type(8)));
typedef _Float16 f16x4 __attribute__((ext_vector_type(4)));
typedef float f32x4 __attribute__((ext_vector_type(4)));

// block per (ngrp, p, bhalf): lane = n (coalesced 128B stores); 8 b's per block.
__global__ __launch_bounds__(256) void embedq6_k(
    const float* __restrict__ src, const float* __restrict__ vw,
    _Float16* __restrict__ xqT)
{
    int p = blockIdx.y;
    int n0 = blockIdx.x * 64;
    int bh = blockIdx.z;              // b in [bh*8, bh*8+8)
    int t = threadIdx.x;
    int lane = t & 63, wid = t >> 6;
    __shared__ float sv[96][64];      // [(b-bh*8)*12+tt][n]
    __shared__ float wvs[PL*HID];
    __shared__ float pe[64];
    for (int r = wid; r < 96; r += 4) {
        int b = bh*8 + r/12, tt = r % 12;
        sv[r][lane] = src[((size_t)b*TSTEPS + p*PL + tt)*N_NODES + n0 + lane];
    }
    for (int i = t; i < PL*HID; i += 256) wvs[i] = vw[i];
    if (t < 64) {
        float d = expf(-(float)(t & ~1) * (float)(9.210340371976184/64.0));
        float arg = (float)p * d;
        pe[t] = (t & 1) ? cosf(arg) : sinf(arg);
    }
    __syncthreads();
#pragma unroll 1
    for (int bb = 0; bb < 2; ++bb) {
        int br = wid*2 + bb;
        int b = bh*8 + br;
        float svr[12];
#pragma unroll
        for (int tt = 0; tt < 12; ++tt) svr[tt] = sv[br*12 + tt][lane];
        _Float16* xp = xqT + ((size_t)p << 20) + (size_t)b*64*1024 + n0 + lane;
#pragma unroll 1
        for (int h0 = 0; h0 < 64; h0 += 8) {
#pragma unroll
            for (int hh = 0; hh < 8; ++hh) {
                int h = h0 + hh;
                float d = pe[h];
#pragma unroll
                for (int tt = 0; tt < 12; ++tt) d += svr[tt] * wvs[tt*HID + h];
                xp[(size_t)h*1024] = (_Float16)d;
            }
        }
    }
}

// A[n][m] = softmax_m(relu(emb[n]·emb[m])), written as plain f16.
__global__ __launch_bounds__(256) void adj_k(const float* __restrict__ emb,
    _Float16* __restrict__ Ahi)
{
    __shared__ float en[EMB];
    __shared__ float red[256];
    int n = blockIdx.x, t = threadIdx.x;
    if (t < EMB) en[t] = emb[n*EMB + t];
    __syncthreads();
    float v[4]; float mx = 0.f;
#pragma unroll
    for (int q = 0; q < 4; ++q) {
        int m = q*256 + t;
        float dot = 0.f;
#pragma unroll
        for (int e = 0; e < EMB; ++e) dot += en[e]*emb[m*EMB + e];
        v[q] = fmaxf(dot, 0.f);
        mx = fmaxf(mx, v[q]);
    }
    red[t] = mx; __syncthreads();
    for (int s2 = 128; s2 > 0; s2 >>= 1) {
        if (t < s2) red[t] = fmaxf(red[t], red[t + s2]);
        __syncthreads();
    }
    mx = red[0]; __syncthreads();
    float sum = 0.f;
#pragma unroll
    for (int q = 0; q < 4; ++q) { v[q] = expf(v[q] - mx); sum += v[q]; }
    red[t] = sum; __syncthreads();
    for (int s2 = 128; s2 > 0; s2 >>= 1) {
        if (t < s2) red[t] += red[t + s2];
        __syncthreads();
    }
    float inv = 1.f / red[0];
#pragma unroll
    for (int q = 0; q < 4; ++q)
        Ahi[(size_t)n*N_NODES + q*256 + t] = (_Float16)(v[q]*inv);
}

// gwT2[e][kc4][OUT][4] <- gwl[e][kc][o]
template<int OUT>
__global__ __launch_bounds__(256) void wtrans2_k(
    const float* __restrict__ gwl, float* __restrict__ gwT2)
{
    int idx = blockIdx.x*256 + threadIdx.x;
    int o = idx % OUT;
    int rest = idx / OUT;
    int kc = rest & 255;
    int e = rest >> 8;
    gwT2[(((size_t)e*64 + (kc >> 2))*OUT + o)*4 + (kc & 3)] = gwl[idx];
}

// W16[n][kc4][OUT][4] f16 = sum_e emb[n][e]*gwT2[e][kc4][o][kj].
template<int OUT>
__global__ __launch_bounds__(256) void wnodeq3_k(
    const float* __restrict__ emb, const float* __restrict__ gwT2,
    _Float16* __restrict__ W16)
{
    int t = threadIdx.x;
    int n0 = blockIdx.x * 4;
    int y = blockIdx.y;
    const int G = 256/OUT;
    int o = t % OUT, g = t / OUT;
    __shared__ float se[4][EMB];
    if (t < 4*EMB) se[t >> 4][t & 15] = emb[(n0 + (t >> 4))*EMB + (t & 15)];
    __syncthreads();
    for (int kc4 = y*8 + g; kc4 < (y+1)*8; kc4 += G) {
        f32x4 s[4];
#pragma unroll
        for (int ng = 0; ng < 4; ++ng) s[ng] = (f32x4){0.f,0.f,0.f,0.f};
        const float* gp = gwT2 + ((size_t)kc4*OUT + o)*4;
#pragma unroll 4
        for (int e = 0; e < EMB; ++e) {
            f32x4 gv = *(const f32x4*)(gp + (size_t)e*(64*OUT*4));
#pragma unroll
            for (int ng = 0; ng < 4; ++ng) {
                float c = se[ng][e];
                s[ng] += gv * c;
            }
        }
#pragma unroll
        for (int ng = 0; ng < 4; ++ng) {
            f16x4 q;
            q[0] = (_Float16)s[ng][0]; q[1] = (_Float16)s[ng][1];
            q[2] = (_Float16)s[ng][2]; q[3] = (_Float16)s[ng][3];
            *(f16x4*)(W16 + (((size_t)(n0+ng)*64 + kc4)*OUT + o)*4) = q;
        }
    }
}

__global__ __launch_bounds__(256) void bias_k(const float* __restrict__ emb,
                        const float* __restrict__ gbl, float* __restrict__ bn, int OUT)
{
    int idx = blockIdx.x*256 + threadIdx.x;
    if (idx >= N_NODES*OUT) return;
    int n = idx / OUT, o = idx % OUT;
    float s = 0.f;
#pragma unroll
    for (int e = 0; e < EMB; ++e) s += emb[n*EMB + e]*gbl[e*OUT + o];
    bn[idx] = s;
}

// Batched A@x for 8 consecutive steps. grid (16,16,8), f16 out.
__global__ __launch_bounds__(256) void gemmaxb_k(
    const _Float16* __restrict__ Ahi, const _Float16* __restrict__ xqT_b,
    _Float16* __restrict__ pAx16)
{
    int st = blockIdx.z;
    const _Float16* BT16 = xqT_b + ((size_t)st << 20);
    _Float16* out = pAx16 + ((size_t)st << 20);
    __shared__ _Float16 Ash[64*72];
    __shared__ _Float16 Bsh[64*72];
    int t = threadIdx.x;
    int l = t & 63, w = t >> 6;
    int wr = w >> 1, wc = w & 1;
    int r0 = blockIdx.y*64, c0 = blockIdx.x*64;
    f32x4 acc[2][2];
#pragma unroll
    for (int i = 0; i < 2; ++i)
#pragma unroll
        for (int j = 0; j < 2; ++j) acc[i][j] = (f32x4){0.f,0.f,0.f,0.f};
    int arow = wr*32 + (l & 15);
    int brow = wc*32 + (l & 15);
    int koff = (l >> 4)*8;
    for (int k0 = 0; k0 < 1024; k0 += 64) {
        __syncthreads();
#pragma unroll
        for (int c = 0; c < 2; ++c) {
            int id = t + 256*c;
            int row = id >> 3, k8 = id & 7;
            *(f16x8*)(&Ash[row*72 + k8*8]) =
                *(const f16x8*)(&Ahi[(size_t)(r0+row)*1024 + k0 + k8*8]);
            *(f16x8*)(&Bsh[row*72 + k8*8]) =
                *(const f16x8*)(&BT16[(size_t)(c0+row)*1024 + k0 + k8*8]);
        }
        __syncthreads();
#pragma unroll
        for (int kk = 0; kk < 2; ++kk) {
            int ko = kk*32 + koff;
            f16x8 ah0 = *(const f16x8*)(&Ash[(size_t)arow*72 + ko]);
            f16x8 ah1 = *(const f16x8*)(&Ash[(size_t)(arow+16)*72 + ko]);
            f16x8 bh0 = *(const f16x8*)(&Bsh[(size_t)brow*72 + ko]);
            f16x8 bh1 = *(const f16x8*)(&Bsh[(size_t)(brow+16)*72 + ko]);
            acc[0][0] = __builtin_amdgcn_mfma_f32_16x16x32_f16(ah0, bh0, acc[0][0], 0, 0, 0);
            acc[0][1] = __builtin_amdgcn_mfma_f32_16x16x32_f16(ah0, bh1, acc[0][1], 0, 0, 0);
            acc[1][0] = __builtin_amdgcn_mfma_f32_16x16x32_f16(ah1, bh0, acc[1][0], 0, 0, 0);
            acc[1][1] = __builtin_amdgcn_mfma_f32_16x16x32_f16(ah1, bh1, acc[1][1], 0, 0, 0);
        }
    }
#pragma unroll
    for (int fr = 0; fr < 2; ++fr)
#pragma unroll
        for (int fc = 0; fc < 2; ++fc) {
            int orow = r0 + wr*32 + fr*16 + ((l >> 4) << 2);
            int ocol = c0 + wc*32 + fc*16 + (l & 15);
#pragma unroll
            for (int i = 0; i < 4; ++i)
                out[(size_t)(orow+i)*1024 + ocol] = (_Float16)acc[fr][fc][i];
        }
}

// Per-step recurrent GEMMs: job 0: A@hT16 -> pAh; job 1: A@zhT16 -> pAzh.
__global__ __launch_bounds__(256) void gemm16_k(
    const _Float16* __restrict__ Ahi,
    const _Float16* __restrict__ hT16, const _Float16* __restrict__ zhT16,
    float* __restrict__ pAh, float* __restrict__ pAzh, int zoff)
{
    int z = zoff + blockIdx.z;
    int job = z >> 1, ks = z & 1;
    int kbase = ks << 9;
    float* out = (job ? pAzh : pAh) + ((size_t)ks << 20);
    const _Float16* BT16 = job ? zhT16 : hT16;
    __shared__ _Float16 Ash[64*72];
    __shared__ _Float16 Bsh[64*72];
    int t = threadIdx.x;
    int l = t & 63, w = t >> 6;
    int wr = w >> 1, wc = w & 1;
    int r0 = blockIdx.y*64, c0 = blockIdx.x*64;
    f32x4 acc[2][2];
#pragma unroll
    for (int i = 0; i < 2; ++i)
#pragma unroll
        for (int j = 0; j < 2; ++j) acc[i][j] = (f32x4){0.f,0.f,0.f,0.f};
    int arow = wr*32 + (l & 15);
    int brow = wc*32 + (l & 15);
    int koff = (l >> 4)*8;
    for (int k0 = kbase; k0 < kbase + 512; k0 += 64) {
        __syncthreads();
#pragma unroll
        for (int c = 0; c < 2; ++c) {
            int id = t + 256*c;
            int row = id >> 3, k8 = id & 7;
            *(f16x8*)(&Ash[row*72 + k8*8]) =
                *(const f16x8*)(&Ahi[(size_t)(r0+row)*1024 + k0 + k8*8]);
            *(f16x8*)(&Bsh[row*72 + k8*8]) =
                *(const f16x8*)(&BT16[(size_t)(c0+row)*1024 + k0 + k8*8]);
        }
        __syncthreads();
#pragma unroll
        for (int kk = 0; kk < 2; ++kk) {
            int ko = kk*32 + koff;
            f16x8 ah0 = *(const f16x8*)(&Ash[(size_t)arow*72 + ko]);
            f16x8 ah1 = *(const f16x8*)(&Ash[(size_t)(arow+16)*72 + ko]);
            f16x8 bh0 = *(const f16x8*)(&Bsh[(size_t)brow*72 + ko]);
            f16x8 bh1 = *(const f16x8*)(&Bsh[(size_t)(brow+16)*72 + ko]);
            acc[0][0] = __builtin_amdgcn_mfma_f32_16x16x32_f16(ah0, bh0, acc[0][0], 0, 0, 0);
            acc[0][1] = __builtin_amdgcn_mfma_f32_16x16x32_f16(ah0, bh1, acc[0][1], 0, 0, 0);
            acc[1][0] = __builtin_amdgcn_mfma_f32_16x16x32_f16(ah1, bh0, acc[1][0], 0, 0, 0);
            acc[1][1] = __builtin_amdgcn_mfma_f32_16x16x32_f16(ah1, bh1, acc[1][1], 0, 0, 0);
        }
    }
#pragma unroll
    for (int fr = 0; fr < 2; ++fr)
#pragma unroll
        for (int fc = 0; fc < 2; ++fc) {
            int orow = r0 + wr*32 + fr*16 + ((l >> 4) << 2);
            int ocol = c0 + wc*32 + fc*16 + (l & 15);
#pragma unroll
            for (int i = 0; i < 4; ++i)
                out[(size_t)(orow+i)*1024 + ocol] = acc[fr][fc][i];
        }
}

// zr[n][b][o] = sigmoid([x,h,Ax,Ah]·W(o,:) + bg); writes zhT16[j][n]=z*h.
// Split-K within block: g = t>>7 picks k-half, each thread covers ALL 16 b's;
// each weight row read ONCE per block (R16 read each row twice -> L1 thrash).
// g=1 partials combined via LDS; g=0 finishes. f32 split-K sum (same as GEMMs).
template<int FIRST>
__global__ __launch_bounds__(256) void gate_k(
    const _Float16* __restrict__ xqT16p, const _Float16* __restrict__ pAx16,
    const float* __restrict__ hst, const float* __restrict__ pAh,
    const _Float16* __restrict__ W16, const float* __restrict__ bg,
    float* __restrict__ zr, _Float16* __restrict__ zhT16)
{
    __shared__ float inp[16*256];     // 16 KB
    __shared__ float red[128*16];     //  8 KB (g=1 partials)
    int n = ((blockIdx.x & 7) << 7) | (blockIdx.x >> 3);
    int t = threadIdx.x;
    size_t nb = (size_t)n*1024;
    for (int i = t; i < 1024; i += 256) {
        int b = i >> 6, c = i & 63;
        inp[b*256 + c]       = (float)xqT16p[(size_t)i*1024 + n];
        inp[b*256 + 64 + c]  = FIRST ? 0.f : hst[nb + i];
        inp[b*256 + 128 + c] = (float)pAx16[nb + i];
        inp[b*256 + 192 + c] = FIRST ? 0.f : (pAh[nb + i] + pAh[nb + i + 1048576]);
    }
    __syncthreads();
    int o = t & 127, g = t >> 7;      // g = k-half
    const _Float16* wp = W16 + (size_t)n*32768 + o*4 + (size_t)(g*32)*512;
    float acc[16];
#pragma unroll
    for (int u = 0; u < 16; ++u) acc[u] = 0.f;
    for (int kc4 = 0; kc4 < 32; ++kc4) {
        f16x4 w4 = *(const f16x4*)(wp + (size_t)kc4*512);
        float w0 = (float)w4[0], w1 = (float)w4[1], w2 = (float)w4[2], w3 = (float)w4[3];
        int kb = (g*32 + kc4)*4;
#pragma unroll
        for (int u = 0; u < 16; ++u) {
            float4 iv = *(const float4*)(&inp[u*256 + kb]);
            acc[u] += w0*iv.x + w1*iv.y + w2*iv.z + w3*iv.w;
        }
    }
    if (g == 1) {
#pragma unroll
        for (int u = 0; u < 16; ++u) red[o*16 + u] = acc[u];
    }
    __syncthreads();
    if (g == 0) {
        float bias = bg[n*128 + o];
#pragma unroll
        for (int u = 0; u < 16; ++u) {
            float pre = acc[u] + red[o*16 + u] + bias;
            float val = 1.f/(1.f + expf(-pre));
            zr[((size_t)n*16 + u)*128 + o] = val;
            if (!FIRST && o < 64)
                zhT16[(size_t)(u*64 + o)*1024 + n] = (_Float16)(val * inp[u*256 + 64 + o]);
        }
    }
}

// h_new = r*h + (1-r)*tanh([x, z*h, Ax, Azh]·W + bu). Split-K 4-way within
// block (g = t>>6 picks k-quarter); weight rows read once per block.
template<int FIRST, int WX>
__global__ __launch_bounds__(256) void upd_k(
    _Float16* __restrict__ xqT16p, const _Float16* __restrict__ pAx16,
    float* __restrict__ hst, const float* __restrict__ pAzh,
    const float* __restrict__ zr, const _Float16* __restrict__ W16,
    const float* __restrict__ bu, _Float16* __restrict__ hT16)
{
    __shared__ float inp[16*256];     // 16 KB
    __shared__ float red[3*64*16];    // 12 KB (g=1..3 partials)
    int n = ((blockIdx.x & 7) << 7) | (blockIdx.x >> 3);
    int t = threadIdx.x;
    size_t nb = (size_t)n*1024;
    for (int i = t; i < 1024; i += 256) {
        int b = i >> 6, c = i & 63;
        float hv = FIRST ? 0.f : hst[nb + i];
        float zv = zr[((size_t)n*16 + b)*128 + c];
        inp[b*256 + c]       = (float)xqT16p[(size_t)i*1024 + n];
        inp[b*256 + 64 + c]  = zv * hv;
        inp[b*256 + 128 + c] = (float)pAx16[nb + i];
        inp[b*256 + 192 + c] = FIRST ? 0.f : (pAzh[nb + i] + pAzh[nb + i + 1048576]);
    }
    __syncthreads();
    int o = t & 63, g = t >> 6;       // g = k-quarter
    const _Float16* wp = W16 + (size_t)n*16384 + o*4 + (size_t)(g*16)*256;
    float acc[16];
#pragma unroll
    for (int u = 0; u < 16; ++u) acc[u] = 0.f;
    for (int kc4 = 0; kc4 < 16; ++kc4) {
        f16x4 w4 = *(const f16x4*)(wp + (size_t)kc4*256);
        float w0 = (float)w4[0], w1 = (float)w4[1], w2 = (float)w4[2], w3 = (float)w4[3];
        int kb = (g*16 + kc4)*4;
#pragma unroll
        for (int u = 0; u < 16; ++u) {
            float4 iv = *(const float4*)(&inp[u*256 + kb]);
            acc[u] += w0*iv.x + w1*iv.y + w2*iv.z + w3*iv.w;
        }
    }
    if (g > 0) {
#pragma unroll
        for (int u = 0; u < 16; ++u) red[((g-1)*64 + o)*16 + u] = acc[u];
    }
    __syncthreads();
    if (g == 0) {
        float bias = bu[n*64 + o];
#pragma unroll
        for (int u = 0; u < 16; ++u) {
            float s = acc[u] + red[(0*64 + o)*16 + u] + red[(1*64 + o)*16 + u]
                    + red[(2*64 + o)*16 + u] + bias;
            float r = zr[((size_t)n*16 + u)*128 + 64 + o];
            float hold = FIRST ? 0.f : hst[nb + u*64 + o];
            float hc = tanhf(s);
            float hn = r*hold + (1.f - r)*hc;
            hst[nb + u*64 + o] = hn;
            hT16[(size_t)(u*64 + o)*1024 + n] = (_Float16)hn;
            if (WX) xqT16p[(size_t)(u*64 + o)*1024 + n] = (_Float16)hn;
        }
    }
}

// out[b][o][n] = h[n][b][:]·ecw[o][:] + ecb[o]
__global__ __launch_bounds__(256) void endconv_k(
    const float* __restrict__ hst, const float* __restrict__ ecw,
    const float* __restrict__ ecb, float* __restrict__ out)
{
    int idx = blockIdx.x*256 + threadIdx.x;
    int n = idx & 1023;
    int o = (idx >> 10) % HOR;
    int b = idx / (HOR*1024);
    float s = ecb[o];
#pragma unroll
    for (int hh = 0; hh < 64; ++hh)
        s += hst[((size_t)n*16 + b)*64 + hh] * ecw[o*64 + hh];
    out[idx] = s;
}

extern "C" void kernel_launch(void* const* d_in, const int* in_sizes, int n_in,
                              void* d_out, int out_size, void* d_ws, size_t ws_size,
                              hipStream_t stream)
{
    const float* source = (const float*)d_in[0];
    const float* emb    = (const float*)d_in[2];
    const float* vw     = (const float*)d_in[3];
    const float* gate_w = (const float*)d_in[4];
    const float* gate_b = (const float*)d_in[5];
    const float* upd_w  = (const float*)d_in[6];
    const float* upd_b  = (const float*)d_in[7];
    const float* ecw    = (const float*)d_in[8];
    const float* ecb    = (const float*)d_in[9];
    float* out = (float*)d_out;

    // ---- workspace carve: ~195 MB ----
    char* p = (char*)d_ws;
    _Float16* Ahi = (_Float16*)p; p += (size_t)1048576*2;    //   2.0 MB
    _Float16* WgQ = (_Float16*)p; p += (size_t)33554432*2;   //  64.0 MB [n][64][128][4] f16
    _Float16* WuQ = (_Float16*)p; p += (size_t)16777216*2;   //  32.0 MB [n][64][64][4] f16
    float* bgn  = (float*)p;  p += (size_t)131072*4;         //   0.5 MB
    float* bun  = (float*)p;  p += (size_t)65536*4;          //   0.25 MB
    _Float16* xqT = (_Float16*)p; p += (size_t)25165824*2;   //  48.0 MB [p][j][n] f16
    float* hbuf = (float*)p;  p += (size_t)1048576*4;        //   4.0 MB h rows f32
    _Float16* hT16 = (_Float16*)p; p += (size_t)1048576*2;   //   2.0 MB h cols f16
    float* zrb  = (float*)p;  p += (size_t)2097152*4;        //   8.0 MB
    _Float16* zhT16 = (_Float16*)p; p += (size_t)1048576*2;  //   2.0 MB (z*h)^T f16
    float* pAh  = (float*)p;  p += (size_t)2097152*4;        //   8.0 MB split-K pair
    _Float16* pAx16 = (_Float16*)p; p += (size_t)8388608*2;  //  16.0 MB 8-step A@x batch
    float* pAzh = (float*)p;  p += (size_t)2097152*4;        //   8.0 MB split-K pair
    float* gwT2 = pAzh;   // 2 MB scratch, aliases pAzh (dead during layer setup)

    embedq6_k<<<dim3(16,24,2), 256, 0, stream>>>(source, vw, xqT);
    adj_k<<<1024, 256, 0, stream>>>(emb, Ahi);

    for (int l = 0; l < 2; ++l) {
        wtrans2_k<128><<<2048, 256, 0, stream>>>(gate_w + (size_t)l*524288, gwT2);
        wnodeq3_k<128><<<dim3(256,8), 256, 0, stream>>>(emb, gwT2, WgQ);
        wtrans2_k<64><<<1024, 256, 0, stream>>>(upd_w + (size_t)l*262144, gwT2);
        wnodeq3_k<64><<<dim3(256,8), 256, 0, stream>>>(emb, gwT2, WuQ);
        bias_k<<<512, 256, 0, stream>>>(emb, gate_b + l*2048, bgn, 128);
        bias_k<<<256, 256, 0, stream>>>(emb, upd_b + l*1024, bun, 64);
        for (int ps = 0; ps < PWIN; ++ps) {
            _Float16* xqT_p = xqT + ((size_t)ps << 20);
            _Float16* pAx_p = pAx16 + ((size_t)(ps & 7) << 20);
            if ((ps & 7) == 0)
                gemmaxb_k<<<dim3(16,16,8), 256, 0, stream>>>(Ahi, xqT_p, pAx16);
            if (ps == 0) {
                gate_k<1><<<1024, 256, 0, stream>>>(xqT_p, pAx_p, hbuf, pAh, WgQ, bgn, zrb, zhT16);
                if (l == 0)
                    upd_k<1,1><<<1024, 256, 0, stream>>>(xqT_p, pAx_p, hbuf, pAzh, zrb, WuQ, bun, hT16);
                else
                    upd_k<1,0><<<1024, 256, 0, stream>>>(xqT_p, pAx_p, hbuf, pAzh, zrb, WuQ, bun, hT16);
            } else {
                gemm16_k<<<dim3(16,16,2), 256, 0, stream>>>(Ahi, hT16, zhT16, pAh, pAzh, 0);
                gate_k<0><<<1024, 256, 0, stream>>>(xqT_p, pAx_p, hbuf, pAh, WgQ, bgn, zrb, zhT16);
                gemm16_k<<<dim3(16,16,2), 256, 0, stream>>>(Ahi, hT16, zhT16, pAh, pAzh, 2);
                if (l == 0)
                    upd_k<0,1><<<1024, 256, 0, stream>>>(xqT_p, pAx_p, hbuf, pAzh, zrb, WuQ, bun, hT16);
                else
                    upd_k<0,0><<<1024, 256, 0, stream>>>(xqT_p, pAx_p, hbuf, pAzh, zrb, WuQ, bun, hT16);
            }
        }
    }
    endconv_k<<<768, 256, 0, stream>>>(hbuf, ecw, ecb, out);
}

// Round 19
// 2920.284 us; speedup vs baseline: 1.7325x; 1.4002x over previous
//
#include <hip/hip_runtime.h>
#include <math.h>

#define N_NODES 1024
#define HID 64
#define BATCH 16
#define TSTEPS 288
#define PWIN 24
#define PL 12
#define EMB 16
#define HOR 12

typedef __attribute__((ext_vector_type(4))) short short4_t;
typedef _Float16 f16x8 __attribute__((ext_vector_type(8)));
typedef _Float16 f16x4 __attribute__((ext_vector_type(4)));
typedef float f32x4 __attribute__((ext_vector_type(4)));

// block per (ngrp, p, bhalf): lane = n (coalesced 128B stores); 8 b's per block.
__global__ __launch_bounds__(256) void embedq6_k(
    const float* __restrict__ src, const float* __restrict__ vw,
    _Float16* __restrict__ xqT)
{
    int p = blockIdx.y;
    int n0 = blockIdx.x * 64;
    int bh = blockIdx.z;              // b in [bh*8, bh*8+8)
    int t = threadIdx.x;
    int lane = t & 63, wid = t >> 6;
    __shared__ float sv[96][64];      // [(b-bh*8)*12+tt][n]
    __shared__ float wvs[PL*HID];
    __shared__ float pe[64];
    for (int r = wid; r < 96; r += 4) {
        int b = bh*8 + r/12, tt = r % 12;
        sv[r][lane] = src[((size_t)b*TSTEPS + p*PL + tt)*N_NODES + n0 + lane];
    }
    for (int i = t; i < PL*HID; i += 256) wvs[i] = vw[i];
    if (t < 64) {
        float d = expf(-(float)(t & ~1) * (float)(9.210340371976184/64.0));
        float arg = (float)p * d;
        pe[t] = (t & 1) ? cosf(arg) : sinf(arg);
    }
    __syncthreads();
#pragma unroll 1
    for (int bb = 0; bb < 2; ++bb) {
        int br = wid*2 + bb;
        int b = bh*8 + br;
        float svr[12];
#pragma unroll
        for (int tt = 0; tt < 12; ++tt) svr[tt] = sv[br*12 + tt][lane];
        _Float16* xp = xqT + ((size_t)p << 20) + (size_t)b*64*1024 + n0 + lane;
#pragma unroll 1
        for (int h0 = 0; h0 < 64; h0 += 8) {
#pragma unroll
            for (int hh = 0; hh < 8; ++hh) {
                int h = h0 + hh;
                float d = pe[h];
#pragma unroll
                for (int tt = 0; tt < 12; ++tt) d += svr[tt] * wvs[tt*HID + h];
                xp[(size_t)h*1024] = (_Float16)d;
            }
        }
    }
}

// A[n][m] = softmax_m(relu(emb[n]·emb[m])), written as plain f16.
__global__ __launch_bounds__(256) void adj_k(const float* __restrict__ emb,
    _Float16* __restrict__ Ahi)
{
    __shared__ float en[EMB];
    __shared__ float red[256];
    int n = blockIdx.x, t = threadIdx.x;
    if (t < EMB) en[t] = emb[n*EMB + t];
    __syncthreads();
    float v[4]; float mx = 0.f;
#pragma unroll
    for (int q = 0; q < 4; ++q) {
        int m = q*256 + t;
        float dot = 0.f;
#pragma unroll
        for (int e = 0; e < EMB; ++e) dot += en[e]*emb[m*EMB + e];
        v[q] = fmaxf(dot, 0.f);
        mx = fmaxf(mx, v[q]);
    }
    red[t] = mx; __syncthreads();
    for (int s2 = 128; s2 > 0; s2 >>= 1) {
        if (t < s2) red[t] = fmaxf(red[t], red[t + s2]);
        __syncthreads();
    }
    mx = red[0]; __syncthreads();
    float sum = 0.f;
#pragma unroll
    for (int q = 0; q < 4; ++q) { v[q] = expf(v[q] - mx); sum += v[q]; }
    red[t] = sum; __syncthreads();
    for (int s2 = 128; s2 > 0; s2 >>= 1) {
        if (t < s2) red[t] += red[t + s2];
        __syncthreads();
    }
    float inv = 1.f / red[0];
#pragma unroll
    for (int q = 0; q < 4; ++q)
        Ahi[(size_t)n*N_NODES + q*256 + t] = (_Float16)(v[q]*inv);
}

// gwT2[e][kc4][OUT][4] <- gwl[e][kc][o]
template<int OUT>
__global__ __launch_bounds__(256) void wtrans2_k(
    const float* __restrict__ gwl, float* __restrict__ gwT2)
{
    int idx = blockIdx.x*256 + threadIdx.x;
    int o = idx % OUT;
    int rest = idx / OUT;
    int kc = rest & 255;
    int e = rest >> 8;
    gwT2[(((size_t)e*64 + (kc >> 2))*OUT + o)*4 + (kc & 3)] = gwl[idx];
}

// W16[n][k8][OUT][8] f16 = sum_e emb[n][e]*gwT2[e][kc4][o][kj].
// MFMA-B layout: 8 consecutive k per o (lane f16x8 load in gate/upd).
template<int OUT>
__global__ __launch_bounds__(256) void wnodeq3_k(
    const float* __restrict__ emb, const float* __restrict__ gwT2,
    _Float16* __restrict__ W16)
{
    int t = threadIdx.x;
    int n0 = blockIdx.x * 4;
    int y = blockIdx.y;
    const int G = 256/OUT;
    int o = t % OUT, g = t / OUT;
    __shared__ float se[4][EMB];
    if (t < 4*EMB) se[t >> 4][t & 15] = emb[(n0 + (t >> 4))*EMB + (t & 15)];
    __syncthreads();
    for (int kc4 = y*8 + g; kc4 < (y+1)*8; kc4 += G) {
        f32x4 s[4];
#pragma unroll
        for (int ng = 0; ng < 4; ++ng) s[ng] = (f32x4){0.f,0.f,0.f,0.f};
        const float* gp = gwT2 + ((size_t)kc4*OUT + o)*4;
#pragma unroll 4
        for (int e = 0; e < EMB; ++e) {
            f32x4 gv = *(const f32x4*)(gp + (size_t)e*(64*OUT*4));
#pragma unroll
            for (int ng = 0; ng < 4; ++ng) {
                float c = se[ng][e];
                s[ng] += gv * c;
            }
        }
#pragma unroll
        for (int ng = 0; ng < 4; ++ng) {
            f16x4 q;
            q[0] = (_Float16)s[ng][0]; q[1] = (_Float16)s[ng][1];
            q[2] = (_Float16)s[ng][2]; q[3] = (_Float16)s[ng][3];
            // [n][k8 = kc4>>1][OUT][8], sub-half (kc4&1)*4
            *(f16x4*)(W16 + (((size_t)(n0+ng)*32 + (kc4 >> 1))*OUT + o)*8 + (kc4 & 1)*4) = q;
        }
    }
}

__global__ __launch_bounds__(256) void bias_k(const float* __restrict__ emb,
                        const float* __restrict__ gbl, float* __restrict__ bn, int OUT)
{
    int idx = blockIdx.x*256 + threadIdx.x;
    if (idx >= N_NODES*OUT) return;
    int n = idx / OUT, o = idx % OUT;
    float s = 0.f;
#pragma unroll
    for (int e = 0; e < EMB; ++e) s += emb[n*EMB + e]*gbl[e*OUT + o];
    bn[idx] = s;
}

// Batched A@x for 8 consecutive steps. grid (16,16,8), f16 out.
__global__ __launch_bounds__(256) void gemmaxb_k(
    const _Float16* __restrict__ Ahi, const _Float16* __restrict__ xqT_b,
    _Float16* __restrict__ pAx16)
{
    int st = blockIdx.z;
    const _Float16* BT16 = xqT_b + ((size_t)st << 20);
    _Float16* out = pAx16 + ((size_t)st << 20);
    __shared__ _Float16 Ash[64*72];
    __shared__ _Float16 Bsh[64*72];
    int t = threadIdx.x;
    int l = t & 63, w = t >> 6;
    int wr = w >> 1, wc = w & 1;
    int r0 = blockIdx.y*64, c0 = blockIdx.x*64;
    f32x4 acc[2][2];
#pragma unroll
    for (int i = 0; i < 2; ++i)
#pragma unroll
        for (int j = 0; j < 2; ++j) acc[i][j] = (f32x4){0.f,0.f,0.f,0.f};
    int arow = wr*32 + (l & 15);
    int brow = wc*32 + (l & 15);
    int koff = (l >> 4)*8;
    for (int k0 = 0; k0 < 1024; k0 += 64) {
        __syncthreads();
#pragma unroll
        for (int c = 0; c < 2; ++c) {
            int id = t + 256*c;
            int row = id >> 3, k8 = id & 7;
            *(f16x8*)(&Ash[row*72 + k8*8]) =
                *(const f16x8*)(&Ahi[(size_t)(r0+row)*1024 + k0 + k8*8]);
            *(f16x8*)(&Bsh[row*72 + k8*8]) =
                *(const f16x8*)(&BT16[(size_t)(c0+row)*1024 + k0 + k8*8]);
        }
        __syncthreads();
#pragma unroll
        for (int kk = 0; kk < 2; ++kk) {
            int ko = kk*32 + koff;
            f16x8 ah0 = *(const f16x8*)(&Ash[(size_t)arow*72 + ko]);
            f16x8 ah1 = *(const f16x8*)(&Ash[(size_t)(arow+16)*72 + ko]);
            f16x8 bh0 = *(const f16x8*)(&Bsh[(size_t)brow*72 + ko]);
            f16x8 bh1 = *(const f16x8*)(&Bsh[(size_t)(brow+16)*72 + ko]);
            acc[0][0] = __builtin_amdgcn_mfma_f32_16x16x32_f16(ah0, bh0, acc[0][0], 0, 0, 0);
            acc[0][1] = __builtin_amdgcn_mfma_f32_16x16x32_f16(ah0, bh1, acc[0][1], 0, 0, 0);
            acc[1][0] = __builtin_amdgcn_mfma_f32_16x16x32_f16(ah1, bh0, acc[1][0], 0, 0, 0);
            acc[1][1] = __builtin_amdgcn_mfma_f32_16x16x32_f16(ah1, bh1, acc[1][1], 0, 0, 0);
        }
    }
#pragma unroll
    for (int fr = 0; fr < 2; ++fr)
#pragma unroll
        for (int fc = 0; fc < 2; ++fc) {
            int orow = r0 + wr*32 + fr*16 + ((l >> 4) << 2);
            int ocol = c0 + wc*32 + fc*16 + (l & 15);
#pragma unroll
            for (int i = 0; i < 4; ++i)
                out[(size_t)(orow+i)*1024 + ocol] = (_Float16)acc[fr][fc][i];
        }
}

// Per-step recurrent GEMMs: job 0: A@hT16 -> pAh; job 1: A@zhT16 -> pAzh.
__global__ __launch_bounds__(256) void gemm16_k(
    const _Float16* __restrict__ Ahi,
    const _Float16* __restrict__ hT16, const _Float16* __restrict__ zhT16,
    float* __restrict__ pAh, float* __restrict__ pAzh, int zoff)
{
    int z = zoff + blockIdx.z;
    int job = z >> 1, ks = z & 1;
    int kbase = ks << 9;
    float* out = (job ? pAzh : pAh) + ((size_t)ks << 20);
    const _Float16* BT16 = job ? zhT16 : hT16;
    __shared__ _Float16 Ash[64*72];
    __shared__ _Float16 Bsh[64*72];
    int t = threadIdx.x;
    int l = t & 63, w = t >> 6;
    int wr = w >> 1, wc = w & 1;
    int r0 = blockIdx.y*64, c0 = blockIdx.x*64;
    f32x4 acc[2][2];
#pragma unroll
    for (int i = 0; i < 2; ++i)
#pragma unroll
        for (int j = 0; j < 2; ++j) acc[i][j] = (f32x4){0.f,0.f,0.f,0.f};
    int arow = wr*32 + (l & 15);
    int brow = wc*32 + (l & 15);
    int koff = (l >> 4)*8;
    for (int k0 = kbase; k0 < kbase + 512; k0 += 64) {
        __syncthreads();
#pragma unroll
        for (int c = 0; c < 2; ++c) {
            int id = t + 256*c;
            int row = id >> 3, k8 = id & 7;
            *(f16x8*)(&Ash[row*72 + k8*8]) =
                *(const f16x8*)(&Ahi[(size_t)(r0+row)*1024 + k0 + k8*8]);
            *(f16x8*)(&Bsh[row*72 + k8*8]) =
                *(const f16x8*)(&BT16[(size_t)(c0+row)*1024 + k0 + k8*8]);
        }
        __syncthreads();
#pragma unroll
        for (int kk = 0; kk < 2; ++kk) {
            int ko = kk*32 + koff;
            f16x8 ah0 = *(const f16x8*)(&Ash[(size_t)arow*72 + ko]);
            f16x8 ah1 = *(const f16x8*)(&Ash[(size_t)(arow+16)*72 + ko]);
            f16x8 bh0 = *(const f16x8*)(&Bsh[(size_t)brow*72 + ko]);
            f16x8 bh1 = *(const f16x8*)(&Bsh[(size_t)(brow+16)*72 + ko]);
            acc[0][0] = __builtin_amdgcn_mfma_f32_16x16x32_f16(ah0, bh0, acc[0][0], 0, 0, 0);
            acc[0][1] = __builtin_amdgcn_mfma_f32_16x16x32_f16(ah0, bh1, acc[0][1], 0, 0, 0);
            acc[1][0] = __builtin_amdgcn_mfma_f32_16x16x32_f16(ah1, bh0, acc[1][0], 0, 0, 0);
            acc[1][1] = __builtin_amdgcn_mfma_f32_16x16x32_f16(ah1, bh1, acc[1][1], 0, 0, 0);
        }
    }
#pragma unroll
    for (int fr = 0; fr < 2; ++fr)
#pragma unroll
        for (int fc = 0; fc < 2; ++fc) {
            int orow = r0 + wr*32 + fr*16 + ((l >> 4) << 2);
            int ocol = c0 + wc*32 + fc*16 + (l & 15);
#pragma unroll
            for (int i = 0; i < 4; ++i)
                out[(size_t)(orow+i)*1024 + ocol] = acc[fr][fc][i];
        }
}

// MFMA gate: block = node, 4 waves, wave w covers o-tiles {2w, 2w+1}.
// A = inp16 [16 b][256 k] f16 LDS (pad 8 -> 2-way-free banks); B streamed from
// W16 [n][k8][128][8]; C: col=l&15 (o), row=4*(l>>4)+i (b)  [verified gemm16 map].
template<int FIRST>
__global__ __launch_bounds__(256) void gate_k(
    const _Float16* __restrict__ xqT16p, const _Float16* __restrict__ pAx16,
    const float* __restrict__ hst, const float* __restrict__ pAh,
    const _Float16* __restrict__ W16, const float* __restrict__ bg,
    float* __restrict__ zr, _Float16* __restrict__ zhT16)
{
    __shared__ _Float16 inp16[16][264];
    int n = ((blockIdx.x & 7) << 7) | (blockIdx.x >> 3);
    int t = threadIdx.x;
    int l = t & 63, w = t >> 6;
    size_t nb = (size_t)n*1024;
    for (int i = t; i < 1024; i += 256) {
        int b = i >> 6, c = i & 63;
        inp16[b][c]       = xqT16p[(size_t)i*1024 + n];
        inp16[b][64 + c]  = FIRST ? (_Float16)0.f : (_Float16)hst[nb + i];
        inp16[b][128 + c] = pAx16[nb + i];
        inp16[b][192 + c] = FIRST ? (_Float16)0.f
                                  : (_Float16)(pAh[nb + i] + pAh[nb + i + 1048576]);
    }
    __syncthreads();
    int row = l & 15, kq = l >> 4;
    int o0 = w*32 + row, o1 = o0 + 16;
    const _Float16* wb = W16 + (size_t)n*32768;
    f32x4 acc0 = (f32x4){0.f,0.f,0.f,0.f};
    f32x4 acc1 = (f32x4){0.f,0.f,0.f,0.f};
#pragma unroll
    for (int ks = 0; ks < 8; ++ks) {
        int kb = ks*32 + kq*8;
        f16x8 a  = *(const f16x8*)(&inp16[row][kb]);
        f16x8 b0 = *(const f16x8*)(wb + ((size_t)(kb >> 3)*128 + o0)*8);
        f16x8 b1 = *(const f16x8*)(wb + ((size_t)(kb >> 3)*128 + o1)*8);
        acc0 = __builtin_amdgcn_mfma_f32_16x16x32_f16(a, b0, acc0, 0, 0, 0);
        acc1 = __builtin_amdgcn_mfma_f32_16x16x32_f16(a, b1, acc1, 0, 0, 0);
    }
    float bias0 = bg[n*128 + o0];
    float bias1 = bg[n*128 + o1];
#pragma unroll
    for (int i = 0; i < 4; ++i) {
        int b = kq*4 + i;
        float v0 = 1.f/(1.f + expf(-(acc0[i] + bias0)));
        float v1 = 1.f/(1.f + expf(-(acc1[i] + bias1)));
        zr[((size_t)n*16 + b)*128 + o0] = v0;
        zr[((size_t)n*16 + b)*128 + o1] = v1;
        if (!FIRST && o1 < 64) {   // waves 0,1: both o0,o1 in z-range
            zhT16[(size_t)(b*64 + o0)*1024 + n] = (_Float16)(v0 * (float)inp16[b][64 + o0]);
            zhT16[(size_t)(b*64 + o1)*1024 + n] = (_Float16)(v1 * (float)inp16[b][64 + o1]);
        }
    }
}

// MFMA upd: block = node, 4 waves, wave w covers o-tile w (o = 16w + row).
template<int FIRST, int WX>
__global__ __launch_bounds__(256) void upd_k(
    _Float16* __restrict__ xqT16p, const _Float16* __restrict__ pAx16,
    float* __restrict__ hst, const float* __restrict__ pAzh,
    const float* __restrict__ zr, const _Float16* __restrict__ W16,
    const float* __restrict__ bu, _Float16* __restrict__ hT16)
{
    __shared__ _Float16 inp16[16][264];
    int n = ((blockIdx.x & 7) << 7) | (blockIdx.x >> 3);
    int t = threadIdx.x;
    int l = t & 63, w = t >> 6;
    size_t nb = (size_t)n*1024;
    for (int i = t; i < 1024; i += 256) {
        int b = i >> 6, c = i & 63;
        float hv = FIRST ? 0.f : hst[nb + i];
        float zv = zr[((size_t)n*16 + b)*128 + c];
        inp16[b][c]       = xqT16p[(size_t)i*1024 + n];
        inp16[b][64 + c]  = (_Float16)(zv * hv);
        inp16[b][128 + c] = pAx16[nb + i];
        inp16[b][192 + c] = FIRST ? (_Float16)0.f
                                  : (_Float16)(pAzh[nb + i] + pAzh[nb + i + 1048576]);
    }
    __syncthreads();
    int row = l & 15, kq = l >> 4;
    int o = w*16 + row;
    const _Float16* wb = W16 + (size_t)n*16384;
    f32x4 acc = (f32x4){0.f,0.f,0.f,0.f};
#pragma unroll
    for (int ks = 0; ks < 8; ++ks) {
        int kb = ks*32 + kq*8;
        f16x8 a  = *(const f16x8*)(&inp16[row][kb]);
        f16x8 bv = *(const f16x8*)(wb + ((size_t)(kb >> 3)*64 + o)*8);
        acc = __builtin_amdgcn_mfma_f32_16x16x32_f16(a, bv, acc, 0, 0, 0);
    }
    float bias = bu[n*64 + o];
#pragma unroll
    for (int i = 0; i < 4; ++i) {
        int b = kq*4 + i;
        float r = zr[((size_t)n*16 + b)*128 + 64 + o];
        float hold = FIRST ? 0.f : hst[nb + b*64 + o];
        float hc = tanhf(acc[i] + bias);
        float hn = r*hold + (1.f - r)*hc;
        hst[nb + b*64 + o] = hn;
        hT16[(size_t)(b*64 + o)*1024 + n] = (_Float16)hn;
        if (WX) xqT16p[(size_t)(b*64 + o)*1024 + n] = (_Float16)hn;
    }
}

// out[b][o][n] = h[n][b][:]·ecw[o][:] + ecb[o]
__global__ __launch_bounds__(256) void endconv_k(
    const float* __restrict__ hst, const float* __restrict__ ecw,
    const float* __restrict__ ecb, float* __restrict__ out)
{
    int idx = blockIdx.x*256 + threadIdx.x;
    int n = idx & 1023;
    int o = (idx >> 10) % HOR;
    int b = idx / (HOR*1024);
    float s = ecb[o];
#pragma unroll
    for (int hh = 0; hh < 64; ++hh)
        s += hst[((size_t)n*16 + b)*64 + hh] * ecw[o*64 + hh];
    out[idx] = s;
}

extern "C" void kernel_launch(void* const* d_in, const int* in_sizes, int n_in,
                              void* d_out, int out_size, void* d_ws, size_t ws_size,
                              hipStream_t stream)
{
    const float* source = (const float*)d_in[0];
    const float* emb    = (const float*)d_in[2];
    const float* vw     = (const float*)d_in[3];
    const float* gate_w = (const float*)d_in[4];
    const float* gate_b = (const float*)d_in[5];
    const float* upd_w  = (const float*)d_in[6];
    const float* upd_b  = (const float*)d_in[7];
    const float* ecw    = (const float*)d_in[8];
    const float* ecb    = (const float*)d_in[9];
    float* out = (float*)d_out;

    // ---- workspace carve: ~195 MB ----
    char* p = (char*)d_ws;
    _Float16* Ahi = (_Float16*)p; p += (size_t)1048576*2;    //   2.0 MB
    _Float16* WgQ = (_Float16*)p; p += (size_t)33554432*2;   //  64.0 MB [n][32][128][8] f16
    _Float16* WuQ = (_Float16*)p; p += (size_t)16777216*2;   //  32.0 MB [n][32][64][8] f16
    float* bgn  = (float*)p;  p += (size_t)131072*4;         //   0.5 MB
    float* bun  = (float*)p;  p += (size_t)65536*4;          //   0.25 MB
    _Float16* xqT = (_Float16*)p; p += (size_t)25165824*2;   //  48.0 MB [p][j][n] f16
    float* hbuf = (float*)p;  p += (size_t)1048576*4;        //   4.0 MB h rows f32
    _Float16* hT16 = (_Float16*)p; p += (size_t)1048576*2;   //   2.0 MB h cols f16
    float* zrb  = (float*)p;  p += (size_t)2097152*4;        //   8.0 MB
    _Float16* zhT16 = (_Float16*)p; p += (size_t)1048576*2;  //   2.0 MB (z*h)^T f16
    float* pAh  = (float*)p;  p += (size_t)2097152*4;        //   8.0 MB split-K pair
    _Float16* pAx16 = (_Float16*)p; p += (size_t)8388608*2;  //  16.0 MB 8-step A@x batch
    float* pAzh = (float*)p;  p += (size_t)2097152*4;        //   8.0 MB split-K pair
    float* gwT2 = pAzh;   // 2 MB scratch, aliases pAzh (dead during layer setup)

    embedq6_k<<<dim3(16,24,2), 256, 0, stream>>>(source, vw, xqT);
    adj_k<<<1024, 256, 0, stream>>>(emb, Ahi);

    for (int l = 0; l < 2; ++l) {
        wtrans2_k<128><<<2048, 256, 0, stream>>>(gate_w + (size_t)l*524288, gwT2);
        wnodeq3_k<128><<<dim3(256,8), 256, 0, stream>>>(emb, gwT2, WgQ);
        wtrans2_k<64><<<1024, 256, 0, stream>>>(upd_w + (size_t)l*262144, gwT2);
        wnodeq3_k<64><<<dim3(256,8), 256, 0, stream>>>(emb, gwT2, WuQ);
        bias_k<<<512, 256, 0, stream>>>(emb, gate_b + l*2048, bgn, 128);
        bias_k<<<256, 256, 0, stream>>>(emb, upd_b + l*1024, bun, 64);
        for (int ps = 0; ps < PWIN; ++ps) {
            _Float16* xqT_p = xqT + ((size_t)ps << 20);
            _Float16* pAx_p = pAx16 + ((size_t)(ps & 7) << 20);
            if ((ps & 7) == 0)
                gemmaxb_k<<<dim3(16,16,8), 256, 0, stream>>>(Ahi, xqT_p, pAx16);
            if (ps == 0) {
                gate_k<1><<<1024, 256, 0, stream>>>(xqT_p, pAx_p, hbuf, pAh, WgQ, bgn, zrb, zhT16);
                if (l == 0)
                    upd_k<1,1><<<1024, 256, 0, stream>>>(xqT_p, pAx_p, hbuf, pAzh, zrb, WuQ, bun, hT16);
                else
                    upd_k<1,0><<<1024, 256, 0, stream>>>(xqT_p, pAx_p, hbuf, pAzh, zrb, WuQ, bun, hT16);
            } else {
                gemm16_k<<<dim3(16,16,2), 256, 0, stream>>>(Ahi, hT16, zhT16, pAh, pAzh, 0);
                gate_k<0><<<1024, 256, 0, stream>>>(xqT_p, pAx_p, hbuf, pAh, WgQ, bgn, zrb, zhT16);
                gemm16_k<<<dim3(16,16,2), 256, 0, stream>>>(Ahi, hT16, zhT16, pAh, pAzh, 2);
                if (l == 0)
                    upd_k<0,1><<<1024, 256, 0, stream>>>(xqT_p, pAx_p, hbuf, pAzh, zrb, WuQ, bun, hT16);
                else
                    upd_k<0,0><<<1024, 256, 0, stream>>>(xqT_p, pAx_p, hbuf, pAzh, zrb, WuQ, bun, hT16);
            }
        }
    }
    endconv_k<<<768, 256, 0, stream>>>(hbuf, ecw, ecb, out);
}

// Round 20
// 2786.167 us; speedup vs baseline: 1.8159x; 1.0481x over previous
//
#include <hip/hip_runtime.h>
#include <math.h>

#define N_NODES 1024
#define HID 64
#define BATCH 16
#define TSTEPS 288
#define PWIN 24
#define PL 12
#define EMB 16
#define HOR 12

typedef __attribute__((ext_vector_type(4))) short short4_t;
typedef _Float16 f16x8 __attribute__((ext_vector_type(8)));
typedef _Float16 f16x4 __attribute__((ext_vector_type(4)));
typedef float f32x4 __attribute__((ext_vector_type(4)));

// block per (ngrp, p, bhalf): lane = n (coalesced 128B stores); 8 b's per block.
__global__ __launch_bounds__(256) void embedq6_k(
    const float* __restrict__ src, const float* __restrict__ vw,
    _Float16* __restrict__ xqT)
{
    int p = blockIdx.y;
    int n0 = blockIdx.x * 64;
    int bh = blockIdx.z;              // b in [bh*8, bh*8+8)
    int t = threadIdx.x;
    int lane = t & 63, wid = t >> 6;
    __shared__ float sv[96][64];      // [(b-bh*8)*12+tt][n]
    __shared__ float wvs[PL*HID];
    __shared__ float pe[64];
    for (int r = wid; r < 96; r += 4) {
        int b = bh*8 + r/12, tt = r % 12;
        sv[r][lane] = src[((size_t)b*TSTEPS + p*PL + tt)*N_NODES + n0 + lane];
    }
    for (int i = t; i < PL*HID; i += 256) wvs[i] = vw[i];
    if (t < 64) {
        float d = expf(-(float)(t & ~1) * (float)(9.210340371976184/64.0));
        float arg = (float)p * d;
        pe[t] = (t & 1) ? cosf(arg) : sinf(arg);
    }
    __syncthreads();
#pragma unroll 1
    for (int bb = 0; bb < 2; ++bb) {
        int br = wid*2 + bb;
        int b = bh*8 + br;
        float svr[12];
#pragma unroll
        for (int tt = 0; tt < 12; ++tt) svr[tt] = sv[br*12 + tt][lane];
        _Float16* xp = xqT + ((size_t)p << 20) + (size_t)b*64*1024 + n0 + lane;
#pragma unroll 1
        for (int h0 = 0; h0 < 64; h0 += 8) {
#pragma unroll
            for (int hh = 0; hh < 8; ++hh) {
                int h = h0 + hh;
                float d = pe[h];
#pragma unroll
                for (int tt = 0; tt < 12; ++tt) d += svr[tt] * wvs[tt*HID + h];
                xp[(size_t)h*1024] = (_Float16)d;
            }
        }
    }
}

// A[n][m] = softmax_m(relu(emb[n]·emb[m])), written as plain f16.
__global__ __launch_bounds__(256) void adj_k(const float* __restrict__ emb,
    _Float16* __restrict__ Ahi)
{
    __shared__ float en[EMB];
    __shared__ float red[256];
    int n = blockIdx.x, t = threadIdx.x;
    if (t < EMB) en[t] = emb[n*EMB + t];
    __syncthreads();
    float v[4]; float mx = 0.f;
#pragma unroll
    for (int q = 0; q < 4; ++q) {
        int m = q*256 + t;
        float dot = 0.f;
#pragma unroll
        for (int e = 0; e < EMB; ++e) dot += en[e]*emb[m*EMB + e];
        v[q] = fmaxf(dot, 0.f);
        mx = fmaxf(mx, v[q]);
    }
    red[t] = mx; __syncthreads();
    for (int s2 = 128; s2 > 0; s2 >>= 1) {
        if (t < s2) red[t] = fmaxf(red[t], red[t + s2]);
        __syncthreads();
    }
    mx = red[0]; __syncthreads();
    float sum = 0.f;
#pragma unroll
    for (int q = 0; q < 4; ++q) { v[q] = expf(v[q] - mx); sum += v[q]; }
    red[t] = sum; __syncthreads();
    for (int s2 = 128; s2 > 0; s2 >>= 1) {
        if (t < s2) red[t] += red[t + s2];
        __syncthreads();
    }
    float inv = 1.f / red[0];
#pragma unroll
    for (int q = 0; q < 4; ++q)
        Ahi[(size_t)n*N_NODES + q*256 + t] = (_Float16)(v[q]*inv);
}

// gwT2[e][kc4][OUT][4] <- gwl[e][kc][o]
template<int OUT>
__global__ __launch_bounds__(256) void wtrans2_k(
    const float* __restrict__ gwl, float* __restrict__ gwT2)
{
    int idx = blockIdx.x*256 + threadIdx.x;
    int o = idx % OUT;
    int rest = idx / OUT;
    int kc = rest & 255;
    int e = rest >> 8;
    gwT2[(((size_t)e*64 + (kc >> 2))*OUT + o)*4 + (kc & 3)] = gwl[idx];
}

// W16[n][k8][OUT][8] f16 = sum_e emb[n][e]*gwT2[e][kc4][o][kj].
template<int OUT>
__global__ __launch_bounds__(256) void wnodeq3_k(
    const float* __restrict__ emb, const float* __restrict__ gwT2,
    _Float16* __restrict__ W16)
{
    int t = threadIdx.x;
    int n0 = blockIdx.x * 4;
    int y = blockIdx.y;
    const int G = 256/OUT;
    int o = t % OUT, g = t / OUT;
    __shared__ float se[4][EMB];
    if (t < 4*EMB) se[t >> 4][t & 15] = emb[(n0 + (t >> 4))*EMB + (t & 15)];
    __syncthreads();
    for (int kc4 = y*8 + g; kc4 < (y+1)*8; kc4 += G) {
        f32x4 s[4];
#pragma unroll
        for (int ng = 0; ng < 4; ++ng) s[ng] = (f32x4){0.f,0.f,0.f,0.f};
        const float* gp = gwT2 + ((size_t)kc4*OUT + o)*4;
#pragma unroll 4
        for (int e = 0; e < EMB; ++e) {
            f32x4 gv = *(const f32x4*)(gp + (size_t)e*(64*OUT*4));
#pragma unroll
            for (int ng = 0; ng < 4; ++ng) {
                float c = se[ng][e];
                s[ng] += gv * c;
            }
        }
#pragma unroll
        for (int ng = 0; ng < 4; ++ng) {
            f16x4 q;
            q[0] = (_Float16)s[ng][0]; q[1] = (_Float16)s[ng][1];
            q[2] = (_Float16)s[ng][2]; q[3] = (_Float16)s[ng][3];
            // [n][k8 = kc4>>1][OUT][8], sub-half (kc4&1)*4
            *(f16x4*)(W16 + (((size_t)(n0+ng)*32 + (kc4 >> 1))*OUT + o)*8 + (kc4 & 1)*4) = q;
        }
    }
}

__global__ __launch_bounds__(256) void bias_k(const float* __restrict__ emb,
                        const float* __restrict__ gbl, float* __restrict__ bn, int OUT)
{
    int idx = blockIdx.x*256 + threadIdx.x;
    if (idx >= N_NODES*OUT) return;
    int n = idx / OUT, o = idx % OUT;
    float s = 0.f;
#pragma unroll
    for (int e = 0; e < EMB; ++e) s += emb[n*EMB + e]*gbl[e*OUT + o];
    bn[idx] = s;
}

// Batched A@x for 8 consecutive steps. grid (16,16,8), f16 out.
__global__ __launch_bounds__(256) void gemmaxb_k(
    const _Float16* __restrict__ Ahi, const _Float16* __restrict__ xqT_b,
    _Float16* __restrict__ pAx16)
{
    int st = blockIdx.z;
    const _Float16* BT16 = xqT_b + ((size_t)st << 20);
    _Float16* out = pAx16 + ((size_t)st << 20);
    __shared__ _Float16 Ash[64*72];
    __shared__ _Float16 Bsh[64*72];
    int t = threadIdx.x;
    int l = t & 63, w = t >> 6;
    int wr = w >> 1, wc = w & 1;
    int r0 = blockIdx.y*64, c0 = blockIdx.x*64;
    f32x4 acc[2][2];
#pragma unroll
    for (int i = 0; i < 2; ++i)
#pragma unroll
        for (int j = 0; j < 2; ++j) acc[i][j] = (f32x4){0.f,0.f,0.f,0.f};
    int arow = wr*32 + (l & 15);
    int brow = wc*32 + (l & 15);
    int koff = (l >> 4)*8;
    for (int k0 = 0; k0 < 1024; k0 += 64) {
        __syncthreads();
#pragma unroll
        for (int c = 0; c < 2; ++c) {
            int id = t + 256*c;
            int row = id >> 3, k8 = id & 7;
            *(f16x8*)(&Ash[row*72 + k8*8]) =
                *(const f16x8*)(&Ahi[(size_t)(r0+row)*1024 + k0 + k8*8]);
            *(f16x8*)(&Bsh[row*72 + k8*8]) =
                *(const f16x8*)(&BT16[(size_t)(c0+row)*1024 + k0 + k8*8]);
        }
        __syncthreads();
#pragma unroll
        for (int kk = 0; kk < 2; ++kk) {
            int ko = kk*32 + koff;
            f16x8 ah0 = *(const f16x8*)(&Ash[(size_t)arow*72 + ko]);
            f16x8 ah1 = *(const f16x8*)(&Ash[(size_t)(arow+16)*72 + ko]);
            f16x8 bh0 = *(const f16x8*)(&Bsh[(size_t)brow*72 + ko]);
            f16x8 bh1 = *(const f16x8*)(&Bsh[(size_t)(brow+16)*72 + ko]);
            acc[0][0] = __builtin_amdgcn_mfma_f32_16x16x32_f16(ah0, bh0, acc[0][0], 0, 0, 0);
            acc[0][1] = __builtin_amdgcn_mfma_f32_16x16x32_f16(ah0, bh1, acc[0][1], 0, 0, 0);
            acc[1][0] = __builtin_amdgcn_mfma_f32_16x16x32_f16(ah1, bh0, acc[1][0], 0, 0, 0);
            acc[1][1] = __builtin_amdgcn_mfma_f32_16x16x32_f16(ah1, bh1, acc[1][1], 0, 0, 0);
        }
    }
#pragma unroll
    for (int fr = 0; fr < 2; ++fr)
#pragma unroll
        for (int fc = 0; fc < 2; ++fc) {
            int orow = r0 + wr*32 + fr*16 + ((l >> 4) << 2);
            int ocol = c0 + wc*32 + fc*16 + (l & 15);
#pragma unroll
            for (int i = 0; i < 4; ++i)
                out[(size_t)(orow+i)*1024 + ocol] = (_Float16)acc[fr][fc][i];
        }
}

// Per-step recurrent GEMMs, split-K=4, f16 partials (x4 buffers of 1M):
// z = zoff + blockIdx.z in 0..7: job = z>>2 (0: A@hT16 -> pAh16; 1: A@zhT16
// -> pAzh16), ks = z&3 selects K-quarter and partial buffer.
__global__ __launch_bounds__(256) void gemm16_k(
    const _Float16* __restrict__ Ahi,
    const _Float16* __restrict__ hT16, const _Float16* __restrict__ zhT16,
    _Float16* __restrict__ pAh16, _Float16* __restrict__ pAzh16, int zoff)
{
    int z = zoff + blockIdx.z;
    int job = z >> 2, ks = z & 3;
    int kbase = ks << 8;
    _Float16* out = (job ? pAzh16 : pAh16) + ((size_t)ks << 20);
    const _Float16* BT16 = job ? zhT16 : hT16;
    __shared__ _Float16 Ash[64*72];
    __shared__ _Float16 Bsh[64*72];
    int t = threadIdx.x;
    int l = t & 63, w = t >> 6;
    int wr = w >> 1, wc = w & 1;
    int r0 = blockIdx.y*64, c0 = blockIdx.x*64;
    f32x4 acc[2][2];
#pragma unroll
    for (int i = 0; i < 2; ++i)
#pragma unroll
        for (int j = 0; j < 2; ++j) acc[i][j] = (f32x4){0.f,0.f,0.f,0.f};
    int arow = wr*32 + (l & 15);
    int brow = wc*32 + (l & 15);
    int koff = (l >> 4)*8;
    for (int k0 = kbase; k0 < kbase + 256; k0 += 64) {
        __syncthreads();
#pragma unroll
        for (int c = 0; c < 2; ++c) {
            int id = t + 256*c;
            int row = id >> 3, k8 = id & 7;
            *(f16x8*)(&Ash[row*72 + k8*8]) =
                *(const f16x8*)(&Ahi[(size_t)(r0+row)*1024 + k0 + k8*8]);
            *(f16x8*)(&Bsh[row*72 + k8*8]) =
                *(const f16x8*)(&BT16[(size_t)(c0+row)*1024 + k0 + k8*8]);
        }
        __syncthreads();
#pragma unroll
        for (int kk = 0; kk < 2; ++kk) {
            int ko = kk*32 + koff;
            f16x8 ah0 = *(const f16x8*)(&Ash[(size_t)arow*72 + ko]);
            f16x8 ah1 = *(const f16x8*)(&Ash[(size_t)(arow+16)*72 + ko]);
            f16x8 bh0 = *(const f16x8*)(&Bsh[(size_t)brow*72 + ko]);
            f16x8 bh1 = *(const f16x8*)(&Bsh[(size_t)(brow+16)*72 + ko]);
            acc[0][0] = __builtin_amdgcn_mfma_f32_16x16x32_f16(ah0, bh0, acc[0][0], 0, 0, 0);
            acc[0][1] = __builtin_amdgcn_mfma_f32_16x16x32_f16(ah0, bh1, acc[0][1], 0, 0, 0);
            acc[1][0] = __builtin_amdgcn_mfma_f32_16x16x32_f16(ah1, bh0, acc[1][0], 0, 0, 0);
            acc[1][1] = __builtin_amdgcn_mfma_f32_16x16x32_f16(ah1, bh1, acc[1][1], 0, 0, 0);
        }
    }
#pragma unroll
    for (int fr = 0; fr < 2; ++fr)
#pragma unroll
        for (int fc = 0; fc < 2; ++fc) {
            int orow = r0 + wr*32 + fr*16 + ((l >> 4) << 2);
            int ocol = c0 + wc*32 + fc*16 + (l & 15);
#pragma unroll
            for (int i = 0; i < 4; ++i)
                out[(size_t)(orow+i)*1024 + ocol] = (_Float16)acc[fr][fc][i];
        }
}

// MFMA gate: block = node, 4 waves, wave w covers o-tiles {2w, 2w+1}.
// Ah = sum of 4 f16 split-K partials. zr stored f16.
template<int FIRST>
__global__ __launch_bounds__(256) void gate_k(
    const _Float16* __restrict__ xqT16p, const _Float16* __restrict__ pAx16,
    const float* __restrict__ hst, const _Float16* __restrict__ pAh16,
    const _Float16* __restrict__ W16, const float* __restrict__ bg,
    _Float16* __restrict__ zr16, _Float16* __restrict__ zhT16)
{
    __shared__ _Float16 inp16[16][264];
    int n = ((blockIdx.x & 7) << 7) | (blockIdx.x >> 3);
    int t = threadIdx.x;
    int l = t & 63, w = t >> 6;
    size_t nb = (size_t)n*1024;
    for (int i = t; i < 1024; i += 256) {
        int b = i >> 6, c = i & 63;
        inp16[b][c]       = xqT16p[(size_t)i*1024 + n];
        inp16[b][64 + c]  = FIRST ? (_Float16)0.f : (_Float16)hst[nb + i];
        inp16[b][128 + c] = pAx16[nb + i];
        inp16[b][192 + c] = FIRST ? (_Float16)0.f
            : (_Float16)((float)pAh16[nb + i] + (float)pAh16[nb + i + 1048576]
                       + (float)pAh16[nb + i + 2097152] + (float)pAh16[nb + i + 3145728]);
    }
    __syncthreads();
    int row = l & 15, kq = l >> 4;
    int o0 = w*32 + row, o1 = o0 + 16;
    const _Float16* wb = W16 + (size_t)n*32768;
    f32x4 acc0 = (f32x4){0.f,0.f,0.f,0.f};
    f32x4 acc1 = (f32x4){0.f,0.f,0.f,0.f};
#pragma unroll
    for (int ks = 0; ks < 8; ++ks) {
        int kb = ks*32 + kq*8;
        f16x8 a  = *(const f16x8*)(&inp16[row][kb]);
        f16x8 b0 = *(const f16x8*)(wb + ((size_t)(kb >> 3)*128 + o0)*8);
        f16x8 b1 = *(const f16x8*)(wb + ((size_t)(kb >> 3)*128 + o1)*8);
        acc0 = __builtin_amdgcn_mfma_f32_16x16x32_f16(a, b0, acc0, 0, 0, 0);
        acc1 = __builtin_amdgcn_mfma_f32_16x16x32_f16(a, b1, acc1, 0, 0, 0);
    }
    float bias0 = bg[n*128 + o0];
    float bias1 = bg[n*128 + o1];
#pragma unroll
    for (int i = 0; i < 4; ++i) {
        int b = kq*4 + i;
        float v0 = 1.f/(1.f + expf(-(acc0[i] + bias0)));
        float v1 = 1.f/(1.f + expf(-(acc1[i] + bias1)));
        zr16[((size_t)n*16 + b)*128 + o0] = (_Float16)v0;
        zr16[((size_t)n*16 + b)*128 + o1] = (_Float16)v1;
        if (!FIRST && o1 < 64) {   // waves 0,1: both o0,o1 in z-range
            zhT16[(size_t)(b*64 + o0)*1024 + n] = (_Float16)(v0 * (float)inp16[b][64 + o0]);
            zhT16[(size_t)(b*64 + o1)*1024 + n] = (_Float16)(v1 * (float)inp16[b][64 + o1]);
        }
    }
}

// MFMA upd: block = node, 4 waves, wave w covers o-tile w.
// Azh = sum of 4 f16 split-K partials; z/r read f16.
template<int FIRST, int WX>
__global__ __launch_bounds__(256) void upd_k(
    _Float16* __restrict__ xqT16p, const _Float16* __restrict__ pAx16,
    float* __restrict__ hst, const _Float16* __restrict__ pAzh16,
    const _Float16* __restrict__ zr16, const _Float16* __restrict__ W16,
    const float* __restrict__ bu, _Float16* __restrict__ hT16)
{
    __shared__ _Float16 inp16[16][264];
    int n = ((blockIdx.x & 7) << 7) | (blockIdx.x >> 3);
    int t = threadIdx.x;
    int l = t & 63, w = t >> 6;
    size_t nb = (size_t)n*1024;
    for (int i = t; i < 1024; i += 256) {
        int b = i >> 6, c = i & 63;
        float hv = FIRST ? 0.f : hst[nb + i];
        float zv = (float)zr16[((size_t)n*16 + b)*128 + c];
        inp16[b][c]       = xqT16p[(size_t)i*1024 + n];
        inp16[b][64 + c]  = (_Float16)(zv * hv);
        inp16[b][128 + c] = pAx16[nb + i];
        inp16[b][192 + c] = FIRST ? (_Float16)0.f
            : (_Float16)((float)pAzh16[nb + i] + (float)pAzh16[nb + i + 1048576]
                       + (float)pAzh16[nb + i + 2097152] + (float)pAzh16[nb + i + 3145728]);
    }
    __syncthreads();
    int row = l & 15, kq = l >> 4;
    int o = w*16 + row;
    const _Float16* wb = W16 + (size_t)n*16384;
    f32x4 acc = (f32x4){0.f,0.f,0.f,0.f};
#pragma unroll
    for (int ks = 0; ks < 8; ++ks) {
        int kb = ks*32 + kq*8;
        f16x8 a  = *(const f16x8*)(&inp16[row][kb]);
        f16x8 bv = *(const f16x8*)(wb + ((size_t)(kb >> 3)*64 + o)*8);
        acc = __builtin_amdgcn_mfma_f32_16x16x32_f16(a, bv, acc, 0, 0, 0);
    }
    float bias = bu[n*64 + o];
#pragma unroll
    for (int i = 0; i < 4; ++i) {
        int b = kq*4 + i;
        float r = (float)zr16[((size_t)n*16 + b)*128 + 64 + o];
        float hold = FIRST ? 0.f : hst[nb + b*64 + o];
        float hc = tanhf(acc[i] + bias);
        float hn = r*hold + (1.f - r)*hc;
        hst[nb + b*64 + o] = hn;
        hT16[(size_t)(b*64 + o)*1024 + n] = (_Float16)hn;
        if (WX) xqT16p[(size_t)(b*64 + o)*1024 + n] = (_Float16)hn;
    }
}

// out[b][o][n] = h[n][b][:]·ecw[o][:] + ecb[o]
__global__ __launch_bounds__(256) void endconv_k(
    const float* __restrict__ hst, const float* __restrict__ ecw,
    const float* __restrict__ ecb, float* __restrict__ out)
{
    int idx = blockIdx.x*256 + threadIdx.x;
    int n = idx & 1023;
    int o = (idx >> 10) % HOR;
    int b = idx / (HOR*1024);
    float s = ecb[o];
#pragma unroll
    for (int hh = 0; hh < 64; ++hh)
        s += hst[((size_t)n*16 + b)*64 + hh] * ecw[o*64 + hh];
    out[idx] = s;
}

extern "C" void kernel_launch(void* const* d_in, const int* in_sizes, int n_in,
                              void* d_out, int out_size, void* d_ws, size_t ws_size,
                              hipStream_t stream)
{
    const float* source = (const float*)d_in[0];
    const float* emb    = (const float*)d_in[2];
    const float* vw     = (const float*)d_in[3];
    const float* gate_w = (const float*)d_in[4];
    const float* gate_b = (const float*)d_in[5];
    const float* upd_w  = (const float*)d_in[6];
    const float* upd_b  = (const float*)d_in[7];
    const float* ecw    = (const float*)d_in[8];
    const float* ecb    = (const float*)d_in[9];
    float* out = (float*)d_out;

    // ---- workspace carve: ~185 MB ----
    char* p = (char*)d_ws;
    _Float16* Ahi = (_Float16*)p; p += (size_t)1048576*2;    //   2.0 MB
    _Float16* WgQ = (_Float16*)p; p += (size_t)33554432*2;   //  64.0 MB [n][32][128][8] f16
    _Float16* WuQ = (_Float16*)p; p += (size_t)16777216*2;   //  32.0 MB [n][32][64][8] f16
    float* bgn  = (float*)p;  p += (size_t)131072*4;         //   0.5 MB
    float* bun  = (float*)p;  p += (size_t)65536*4;          //   0.25 MB
    _Float16* xqT = (_Float16*)p; p += (size_t)25165824*2;   //  48.0 MB [p][j][n] f16
    float* hbuf = (float*)p;  p += (size_t)1048576*4;        //   4.0 MB h rows f32
    _Float16* hT16 = (_Float16*)p; p += (size_t)1048576*2;   //   2.0 MB h cols f16
    _Float16* zrb16 = (_Float16*)p; p += (size_t)2097152*2;  //   4.0 MB z/r f16
    _Float16* zhT16 = (_Float16*)p; p += (size_t)1048576*2;  //   2.0 MB (z*h)^T f16
    _Float16* pAh16 = (_Float16*)p; p += (size_t)4194304*2;  //   8.0 MB 4x split-K f16
    _Float16* pAx16 = (_Float16*)p; p += (size_t)8388608*2;  //  16.0 MB 8-step A@x batch
    _Float16* pAzh16 = (_Float16*)p; p += (size_t)4194304*2; //   8.0 MB 4x split-K f16
    float* gwT2 = (float*)pAzh16;  // 2 MB scratch, aliases pAzh16 (dead in setup)

    embedq6_k<<<dim3(16,24,2), 256, 0, stream>>>(source, vw, xqT);
    adj_k<<<1024, 256, 0, stream>>>(emb, Ahi);

    for (int l = 0; l < 2; ++l) {
        wtrans2_k<128><<<2048, 256, 0, stream>>>(gate_w + (size_t)l*524288, gwT2);
        wnodeq3_k<128><<<dim3(256,8), 256, 0, stream>>>(emb, gwT2, WgQ);
        wtrans2_k<64><<<1024, 256, 0, stream>>>(upd_w + (size_t)l*262144, gwT2);
        wnodeq3_k<64><<<dim3(256,8), 256, 0, stream>>>(emb, gwT2, WuQ);
        bias_k<<<512, 256, 0, stream>>>(emb, gate_b + l*2048, bgn, 128);
        bias_k<<<256, 256, 0, stream>>>(emb, upd_b + l*1024, bun, 64);
        for (int ps = 0; ps < PWIN; ++ps) {
            _Float16* xqT_p = xqT + ((size_t)ps << 20);
            _Float16* pAx_p = pAx16 + ((size_t)(ps & 7) << 20);
            if ((ps & 7) == 0)
                gemmaxb_k<<<dim3(16,16,8), 256, 0, stream>>>(Ahi, xqT_p, pAx16);
            if (ps == 0) {
                gate_k<1><<<1024, 256, 0, stream>>>(xqT_p, pAx_p, hbuf, pAh16, WgQ, bgn, zrb16, zhT16);
                if (l == 0)
                    upd_k<1,1><<<1024, 256, 0, stream>>>(xqT_p, pAx_p, hbuf, pAzh16, zrb16, WuQ, bun, hT16);
                else
                    upd_k<1,0><<<1024, 256, 0, stream>>>(xqT_p, pAx_p, hbuf, pAzh16, zrb16, WuQ, bun, hT16);
            } else {
                gemm16_k<<<dim3(16,16,4), 256, 0, stream>>>(Ahi, hT16, zhT16, pAh16, pAzh16, 0);
                gate_k<0><<<1024, 256, 0, stream>>>(xqT_p, pAx_p, hbuf, pAh16, WgQ, bgn, zrb16, zhT16);
                gemm16_k<<<dim3(16,16,4), 256, 0, stream>>>(Ahi, hT16, zhT16, pAh16, pAzh16, 4);
                if (l == 0)
                    upd_k<0,1><<<1024, 256, 0, stream>>>(xqT_p, pAx_p, hbuf, pAzh16, zrb16, WuQ, bun, hT16);
                else
                    upd_k<0,0><<<1024, 256, 0, stream>>>(xqT_p, pAx_p, hbuf, pAzh16, zrb16, WuQ, bun, hT16);
            }
        }
    }
    endconv_k<<<768, 256, 0, stream>>>(hbuf, ecw, ecb, out);
}